// Round 10
// baseline (604.017 us; speedup 1.0000x reference)
//
#include <hip/hip_runtime.h>
#include <hip/hip_bf16.h>
#include <math.h>

typedef __hip_bfloat16 bf16;
typedef unsigned short ushort_t;
typedef __attribute__((ext_vector_type(8))) short short8;
typedef __attribute__((ext_vector_type(4))) float f32x4;

__device__ __forceinline__ float b2f(bf16 v) { return __bfloat162float(v); }
__device__ __forceinline__ bf16 f2b(float v) { return __float2bfloat16(v); }
__device__ __forceinline__ float sigmoidf_(float x) { return 1.0f / (1.0f + __expf(-x)); }

// fast exact-gelu: erf via Abramowitz-Stegun 7.1.26 (|err| <= 1.5e-7)
__device__ __forceinline__ float geluf(float x) {
    float z = x * 0.70710678118654752f;
    float az = fabsf(z);
    float t = 1.0f / (1.0f + 0.3275911f * az);
    float poly = ((((1.061405429f * t - 1.453152027f) * t + 1.421413741f) * t
                   - 0.284496736f) * t + 0.254829592f) * t;
    float erfa = 1.0f - poly * __expf(-z * z);
    float er = (z < 0.f) ? -erfa : erfa;
    return 0.5f * x * (1.0f + er);
}

__device__ __forceinline__ unsigned pack2bf(float a, float b) {
    unsigned ua = __float_as_uint(a); ua = (ua + 0x7FFFu + ((ua >> 16) & 1u)) >> 16;
    unsigned ub = __float_as_uint(b); ub = (ub + 0x7FFFu + ((ub >> 16) & 1u)) >> 16;
    return ua | (ub << 16);
}
__device__ __forceinline__ ushort_t f2bu(float v) {
    unsigned u = __float_as_uint(v);
    u = (u + 0x7FFFu + ((u >> 16) & 1u)) >> 16;
    return (ushort_t)u;
}

// ========================== K0a: dtype detector ==============================
__global__ __launch_bounds__(256) void k_detect(const unsigned* __restrict__ x, int* __restrict__ flag)
{
    __shared__ int cnt;
    if (threadIdx.x == 0) cnt = 0;
    __syncthreads();
    unsigned u = x[threadIdx.x] & 0xFFFFu;
    float f = __uint_as_float(u << 16);
    float a = fabsf(f);
    int sane = (f == 0.0f) || (a > 1e-8f && a < 1e4f);
    atomicAdd(&cnt, sane);
    __syncthreads();
    if (threadIdx.x == 0) *flag = (cnt >= 160) ? 1 : 0;
}

// ========================== K0b: canonicalize to fp32 ========================
struct InPtrs { const void* p[35]; };
struct InOffs { int off[35]; int sz[35]; };

__global__ __launch_bounds__(256) void k_convert(InPtrs P, InOffs O, int total,
                                                 const int* __restrict__ flag,
                                                 float* __restrict__ cvt)
{
    int idx = blockIdx.x * 256 + threadIdx.x;
    if (idx >= total) return;
    int isb = *flag;
    float v = 0.f;
#pragma unroll 1
    for (int s = 0; s < 35; s++) {
        int rel = idx - O.off[s];
        if (rel >= 0 && rel < O.sz[s]) {
            v = isb ? b2f(((const bf16*)P.p[s])[rel]) : ((const float*)P.p[s])[rel];
            break;
        }
    }
    cvt[idx] = v;
}

// ========================== K0c: pack weights to bf16 ========================
// uint regions: qw 12288 | ow 4096 | f1w 8192 | f2w 8192 | gwih 12288 | gwhh 12288
//             | conv2 wt [tap][d][ic] 5120
__global__ __launch_bounds__(256) void k_pack(const float* __restrict__ qw, const float* __restrict__ ow,
                                              const float* __restrict__ f1w, const float* __restrict__ f2w,
                                              const float* __restrict__ gwih, const float* __restrict__ gwhh,
                                              const float* __restrict__ c2w,
                                              unsigned* __restrict__ dst)
{
    int i = blockIdx.x * 256 + threadIdx.x;
    if (i >= 62464) return;
    if (i >= 57344) {
        int j0 = (i - 57344) * 2;
        int tap = j0 >> 11, rem = j0 & 2047;
        int d = rem >> 5, ic = rem & 31;
        dst[i] = pack2bf(c2w[d * 160 + ic * 5 + tap], c2w[d * 160 + (ic + 1) * 5 + tap]);
        return;
    }
    const float* s; int rel;
    if (i < 12288)      { s = qw;   rel = i; }
    else if (i < 16384) { s = ow;   rel = i - 12288; }
    else if (i < 24576) { s = f1w;  rel = i - 16384; }
    else if (i < 32768) { s = f2w;  rel = i - 24576; }
    else if (i < 45056) { s = gwih; rel = i - 32768; }
    else                { s = gwhh; rel = i - 45056; }
    dst[i] = pack2bf(s[2 * rel], s[2 * rel + 1]);
}

// ====================== K1: fused front (CNN+havg | pair-FFT) ================
__global__ __launch_bounds__(256) void k_front(
    const float* __restrict__ x,
    const float* __restrict__ c1w, const float* __restrict__ c1b,
    const float* __restrict__ bn1g, const float* __restrict__ bn1b, const float* __restrict__ bn1m, const float* __restrict__ bn1v,
    const float* __restrict__ c2b,
    const float* __restrict__ bn2g, const float* __restrict__ bn2b, const float* __restrict__ bn2m, const float* __restrict__ bn2v,
    const ushort_t* __restrict__ w2pk,
    float* __restrict__ h_main, ushort_t* __restrict__ Xnb, float* __restrict__ hnf)
{
    __shared__ float smem[9984];
    int t = threadIdx.x;
    if (blockIdx.x >= 512) {
        // ---------------- pair-FFT path ----------------
        float* re = smem;
        float* im = smem + 4096;
        float* red = smem + 8192;
        int bc2 = blockIdx.x - 512;            // 0..255
        int b = bc2 >> 3, cp = bc2 & 7;
        const float* xa = x + ((size_t)b * 16 + 2 * cp) * 4096;
        const float* xb = xa + 4096;
        for (int i = t; i < 4096; i += 256) {
            int r = __brev((unsigned)i) >> 20;
            re[r] = xa[i];
            im[r] = xb[i];
        }
        __syncthreads();
        for (int s = 1; s <= 12; s++) {
            int half = 1 << (s - 1);
            float ang = -6.283185307179586f / (float)(1 << s);
            for (int m = t; m < 2048; m += 256) {
                int j = m & (half - 1);
                int pos = ((m >> (s - 1)) << s) | j;
                float sn, cs;
                __sincosf(ang * (float)j, &sn, &cs);
                float ur = re[pos], ui = im[pos];
                float vr = re[pos + half], vi = im[pos + half];
                float tr = vr * cs - vi * sn;
                float ti = vr * sn + vi * cs;
                re[pos] = ur + tr; im[pos] = ui + ti;
                re[pos + half] = ur - tr; im[pos + half] = ui - ti;
            }
            __syncthreads();
        }
        float maga[9], magb[9];
        float ssa = 0.f, ssb = 0.f;
#pragma unroll
        for (int it = 0; it < 9; it++) {
            int k = t + it * 256;
            float ma = 0.f, mb = 0.f;
            if (k <= 2048) {
                int kn = (4096 - k) & 4095;
                float Rk = re[k], Ik = im[k], Rn = re[kn], In = im[kn];
                float ra = 0.5f * (Rk + Rn), ia = 0.5f * (Ik - In);
                float rb = 0.5f * (Ik + In), ib = 0.5f * (Rn - Rk);
                ma = sqrtf(ra * ra + ia * ia);
                mb = sqrtf(rb * rb + ib * ib);
                ssa += ma * ma; ssb += mb * mb;
            }
            maga[it] = ma; magb[it] = mb;
        }
        for (int off = 32; off; off >>= 1) { ssa += __shfl_xor(ssa, off, 64); ssb += __shfl_xor(ssb, off, 64); }
        int w = t >> 6;
        if ((t & 63) == 0) { red[w] = ssa; red[4 + w] = ssb; }
        __syncthreads();
        float inva = 1.0f / (sqrtf(red[0] + red[1] + red[2] + red[3]) + 1e-8f);
        float invb = 1.0f / (sqrtf(red[4] + red[5] + red[6] + red[7]) + 1e-8f);
        ushort_t* rowa = Xnb + ((size_t)b * 16 + 2 * cp) * 2080;
        ushort_t* rowb = rowa + 2080;
#pragma unroll
        for (int it = 0; it < 9; it++) {
            int k = t + it * 256;
            if (k <= 2048) {
                rowa[k] = f2bu(maga[it] * inva);
                rowb[k] = f2bu(magb[it] * invb);
            }
        }
        for (int f = 2049 + t; f < 2080; f += 256) { rowa[f] = 0; rowb[f] = 0; }
        return;
    }
    // ---------------- CNN path ----------------
    float* ubuf = smem;                           // 4352 floats
    ushort_t* h1t = (ushort_t*)(smem + 4352);     // 10400 ushorts (260 rows x 40)
    float* A2s = smem + 9552;
    float* B2s = smem + 9616;
    float* hsum = smem + 9680;                    // 256
    int bc = blockIdx.x;
    int l = t & 63, w = t >> 6;
    int lo = l & 15, quad = l >> 4;

    if (t < 64) {
        float s = bn2g[t] * rsqrtf(bn2v[t] + 1e-5f);
        A2s[t] = s; B2s[t] = (c2b[t] - bn2m[t]) * s + bn2b[t];
    }
    int icp = t & 15;
    float w1r[2][7], A1r[2], B1r[2];
#pragma unroll
    for (int s = 0; s < 2; s++) {
        int ic = icp * 2 + s;
#pragma unroll
        for (int k = 0; k < 7; k++) w1r[s][k] = c1w[ic * 7 + k];
        float sc = bn1g[ic] * rsqrtf(bn1v[ic] + 1e-5f);
        A1r[s] = sc; B1r[s] = (c1b[ic] - bn1m[ic]) * sc + bn1b[ic];
    }
    short8 Afr[4][5];
#pragma unroll
    for (int dt = 0; dt < 4; dt++)
#pragma unroll
        for (int tap = 0; tap < 5; tap++)
            Afr[dt][tap] = *(const short8*)(w2pk + ((tap * 64 + dt * 16 + lo) * 32 + quad * 8));

    const float* xrow = x + (size_t)bc * 4096;
    float rs = 0.f;
    int dd = t & 63, pg = t >> 6;
    for (int tile = 0; tile < 4; tile++) {
        int X0 = 1024 * tile - 11;
        for (int i = t; i < 1056; i += 256) {
            int g = X0 + i;
            ubuf[i] = (g >= 0 && g < 4096) ? xrow[g] : 0.0f;
        }
        __syncthreads();
        for (int pos = (t >> 4); pos < 260; pos += 16) {
            const float4* xw = (const float4*)&ubuf[4 * pos];
            float4 fa = xw[0], fb = xw[1], fc = xw[2];
            float xv[12] = {fa.x, fa.y, fa.z, fa.w, fb.x, fb.y, fb.z, fb.w,
                            fc.x, fc.y, fc.z, fc.w};
            int t1pg = tile * 256 + pos - 2;
            bool ok = (t1pg >= 0 && t1pg < 1024);
            float res[2];
#pragma unroll
            for (int s = 0; s < 2; s++) {
                float a0 = 0.f, a1 = 0.f, a2 = 0.f, a3 = 0.f;
#pragma unroll
                for (int k = 0; k < 7; k++) {
                    float wv = w1r[s][k];
                    a0 += xv[k] * wv;     a1 += xv[k + 1] * wv;
                    a2 += xv[k + 2] * wv; a3 += xv[k + 3] * wv;
                }
                float A = A1r[s], B = B1r[s];
                a0 = a0 * A + B; a1 = a1 * A + B; a2 = a2 * A + B; a3 = a3 * A + B;
                float mx = fmaxf(fmaxf(a0, a1), fmaxf(a2, a3));
                float mn = fminf(fminf(a0, a1), fminf(a2, a3));
                res[s] = ok ? fmaxf(geluf(mx), geluf(mn)) : 0.0f;
            }
            ((unsigned*)h1t)[pos * 20 + icp] = pack2bf(res[0], res[1]);
        }
        __syncthreads();
        float* houtile = ubuf;
#pragma unroll
        for (int ni = 0; ni < 4; ni++) {
            int nt = w * 4 + ni;
            short8 bfr[5];
#pragma unroll
            for (int tap = 0; tap < 5; tap++)
                bfr[tap] = *(const short8*)&h1t[(nt * 16 + lo + tap) * 40 + quad * 8];
#pragma unroll
            for (int dt = 0; dt < 4; dt++) {
                f32x4 acc = {0.f, 0.f, 0.f, 0.f};
#pragma unroll
                for (int tap = 0; tap < 5; tap++)
                    acc = __builtin_amdgcn_mfma_f32_16x16x32_bf16(Afr[dt][tap], bfr[tap], acc, 0, 0, 0);
                const float4 a2 = *(const float4*)&A2s[dt * 16 + quad * 4];
                const float4 b2 = *(const float4*)&B2s[dt * 16 + quad * 4];
                float a2a[4] = {a2.x, a2.y, a2.z, a2.w};
                float b2a[4] = {b2.x, b2.y, b2.z, b2.w};
#pragma unroll
                for (int r = 0; r < 4; r++) {
                    float v = acc[r] * a2a[r] + b2a[r];
                    float o1 = __shfl_xor(v, 1);
                    float mx = fmaxf(v, o1), mn = fminf(v, o1);
                    float mx2 = __shfl_xor(mx, 2), mn2 = __shfl_xor(mn, 2);
                    mx = fmaxf(mx, mx2); mn = fminf(mn, mn2);
                    float res = fmaxf(geluf(mx), geluf(mn));
                    if ((lo & 3) == 0)
                        houtile[(nt * 4 + (lo >> 2)) * 68 + dt * 16 + quad * 4 + r] = res;
                }
            }
        }
        __syncthreads();
#pragma unroll
        for (int i = 0; i < 16; i++) rs += ubuf[(pg * 16 + i) * 68 + dd];
        float* dst = h_main + (size_t)bc * 16384 + tile * 4096;
        for (int i = t * 4; i < 4096; i += 1024) {
            float4 v = *(const float4*)&ubuf[(i >> 6) * 68 + (i & 63)];
            *(float4*)&dst[i] = v;
        }
        __syncthreads();
    }
    hsum[t] = rs;
    __syncthreads();
    if (t < 64) {
        float avg = (hsum[t] + hsum[64 + t] + hsum[128 + t] + hsum[192 + t]) * (1.0f / 256.0f);
        float tot = avg;
        for (int off = 32; off; off >>= 1) tot += __shfl_xor(tot, off, 64);
        float hc = avg - tot * (1.0f / 64.0f);
        float sq = hc * hc;
        for (int off = 32; off; off >>= 1) sq += __shfl_xor(sq, off, 64);
        hnf[bc * 64 + t] = hc / (sqrtf(sq) + 1e-8f);
    }
}

// =============================== K4: adjacency (MFMA) ========================
__global__ __launch_bounds__(256) void k_adj(
    const ushort_t* __restrict__ Xnb, const float* __restrict__ hnf,
    const float* __restrict__ prior, const float* __restrict__ logw,
    float* __restrict__ adjw, void* __restrict__ out, const int* __restrict__ flag)
{
    __shared__ float tile[4][16][17];
    __shared__ float hh[1024];
    int b = blockIdx.x, t = threadIdx.x;
    int w = t >> 6, l = t & 63;
    int lo = l & 15, quad = l >> 4;
    for (int i = t; i < 1024; i += 256) hh[i] = hnf[b * 1024 + i];
    const ushort_t* base = Xnb + (size_t)b * 16 * 2080 + lo * 2080 + quad * 8;
    f32x4 acc = {0.f, 0.f, 0.f, 0.f};
    for (int kb = w; kb < 65; kb += 4) {
        short8 f = *(const short8*)(base + kb * 32);
        acc = __builtin_amdgcn_mfma_f32_16x16x32_bf16(f, f, acc, 0, 0, 0);
    }
#pragma unroll
    for (int r = 0; r < 4; r++) tile[w][quad * 4 + r][lo] = acc[r];
    __syncthreads();
    int c = t >> 4, e = t & 15;
    float sc = tile[0][c][e] + tile[1][c][e] + tile[2][c][e] + tile[3][c][e];
    float fc = 0.f;
#pragma unroll
    for (int d = 0; d < 64; d++) fc += hh[c * 64 + d] * hh[e * 64 + d];
    float l0 = logw[0], l1 = logw[1], l2 = logw[2];
    float mx = fmaxf(l0, fmaxf(l1, l2));
    float e0 = __expf(l0 - mx), e1 = __expf(l1 - mx), e2 = __expf(l2 - mx);
    float isum = 1.0f / (e0 + e1 + e2);
    float pr = prior[c * 16 + e] + prior[e * 16 + c];
    float v = (e0 * fc + e1 * sc + e2 * pr) * isum;
    adjw[b * 256 + t] = v;
    if (*flag) ((bf16*)out)[4096 + b * 256 + t] = f2b(v);
    else       ((float*)out)[4096 + b * 256 + t] = v;
}

// =============================== K5: GAT stack (MFMA) ========================
// LN computes each lane's OWN A-frag columns (quad*8..+7, 32+quad*8..+7) so
// no LDS redistribution buffer is needed; P and O overlay q's columns in qkb
// (q consumed per head before overwrite, wave-lockstep); vt stride 24->16.
// LDS 72 KB -> 50 KB => 3 blocks/CU.
__device__ __forceinline__ void ln_frag(const float (*ht)[68],
                                        const float* __restrict__ g, const float* __restrict__ bp,
                                        int quad, int lo, short8& a0, short8& a1)
{
    float v[16];
    const float4* r0 = (const float4*)(&ht[lo][quad * 8]);
    const float4* r1 = (const float4*)(&ht[lo][32 + quad * 8]);
    float4 p0 = r0[0], p1 = r0[1], p2 = r1[0], p3 = r1[1];
    v[0] = p0.x; v[1] = p0.y; v[2] = p0.z; v[3] = p0.w;
    v[4] = p1.x; v[5] = p1.y; v[6] = p1.z; v[7] = p1.w;
    v[8] = p2.x; v[9] = p2.y; v[10] = p2.z; v[11] = p2.w;
    v[12] = p3.x; v[13] = p3.y; v[14] = p3.z; v[15] = p3.w;
    float s = 0.f;
#pragma unroll
    for (int i = 0; i < 16; i++) s += v[i];
    s += __shfl_xor(s, 16); s += __shfl_xor(s, 32);
    float mean = s * (1.0f / 64.0f);
    float q = 0.f;
#pragma unroll
    for (int i = 0; i < 16; i++) { float d = v[i] - mean; q += d * d; }
    q += __shfl_xor(q, 16); q += __shfl_xor(q, 32);
    float rstd = rsqrtf(q * (1.0f / 64.0f) + 1e-5f);
    float4 g0 = *(const float4*)(g + quad * 8);
    float4 g1 = *(const float4*)(g + quad * 8 + 4);
    float4 g2 = *(const float4*)(g + 32 + quad * 8);
    float4 g3 = *(const float4*)(g + 32 + quad * 8 + 4);
    float4 b0 = *(const float4*)(bp + quad * 8);
    float4 b1 = *(const float4*)(bp + quad * 8 + 4);
    float4 b2 = *(const float4*)(bp + 32 + quad * 8);
    float4 b3 = *(const float4*)(bp + 32 + quad * 8 + 4);
    float gg[16] = {g0.x, g0.y, g0.z, g0.w, g1.x, g1.y, g1.z, g1.w,
                    g2.x, g2.y, g2.z, g2.w, g3.x, g3.y, g3.z, g3.w};
    float bb[16] = {b0.x, b0.y, b0.z, b0.w, b1.x, b1.y, b1.z, b1.w,
                    b2.x, b2.y, b2.z, b2.w, b3.x, b3.y, b3.z, b3.w};
    union { unsigned u[4]; short8 s8; } c0, c1;
#pragma unroll
    for (int i = 0; i < 4; i++) {
        float oa = (v[2 * i] - mean) * rstd * gg[2 * i] + bb[2 * i];
        float ob = (v[2 * i + 1] - mean) * rstd * gg[2 * i + 1] + bb[2 * i + 1];
        c0.u[i] = pack2bf(oa, ob);
        float oc = (v[8 + 2 * i] - mean) * rstd * gg[8 + 2 * i] + bb[8 + 2 * i];
        float od = (v[9 + 2 * i] - mean) * rstd * gg[9 + 2 * i] + bb[9 + 2 * i];
        c1.u[i] = pack2bf(oc, od);
    }
    a0 = c0.s8;
    a1 = c1.s8;
}

__global__ __launch_bounds__(256) void k_gat(
    const float* __restrict__ hm, const float* __restrict__ adjw,
    const ushort_t* __restrict__ wpk,
    const float* __restrict__ qb_, const float* __restrict__ ob_,
    const float* __restrict__ f1b_, const float* __restrict__ f2b_,
    const float* __restrict__ n1g_, const float* __restrict__ n1b_,
    const float* __restrict__ n2g_, const float* __restrict__ n2b_,
    const float* __restrict__ gng, const float* __restrict__ gnb,
    ushort_t* __restrict__ hmb)
{
    __shared__ float htw_all[4][16][68];
    __shared__ ushort_t qkb_all[4][16][200];
    __shared__ ushort_t vt_all[4][64][16];
    int t = threadIdx.x;
    int w = t >> 6, l = t & 63;
    int quad = l >> 4, lo = l & 15;
    int n = blockIdx.x * 4 + w;
    int b = n >> 8, tp = n & 255;
    float (*htw)[68] = htw_all[w];
    ushort_t (*qkb)[200] = qkb_all[w];
    ushort_t (*vt)[16] = vt_all[w];
    const float* src = hm + (size_t)b * 16 * 16384 + (size_t)tp * 64;
#pragma unroll
    for (int c = 0; c < 16; c++) htw[c][l] = src[(size_t)c * 16384 + l];
    float adjr[4];
#pragma unroll
    for (int r = 0; r < 4; r++) adjr[r] = adjw[b * 256 + (quad * 4 + r) * 16 + lo];

    for (int layer = 0; layer < 2; layer++) {
        const ushort_t* wq  = wpk + layer * 12288;
        const ushort_t* wo  = wpk + 24576 + layer * 4096;
        const ushort_t* wf1 = wpk + 32768 + layer * 8192;
        const ushort_t* wf2 = wpk + 49152 + layer * 8192;
        const float* qb = qb_ + layer * 192;
        const float* ob = ob_ + layer * 64;
        const float* f1b = f1b_ + layer * 128;
        const float* f2b = f2b_ + layer * 64;

        short8 a0, a1;
        ln_frag(htw, n1g_ + layer * 64, n1b_ + layer * 64, quad, lo, a0, a1);

#pragma unroll
        for (int nt = 0; nt < 12; nt++) {
            const ushort_t* wr = wq + (nt * 16 + lo) * 64 + quad * 8;
            short8 b0 = *(const short8*)wr;
            short8 b1 = *(const short8*)(wr + 32);
            f32x4 acc = {0.f, 0.f, 0.f, 0.f};
            acc = __builtin_amdgcn_mfma_f32_16x16x32_bf16(a0, b0, acc, 0, 0, 0);
            acc = __builtin_amdgcn_mfma_f32_16x16x32_bf16(a1, b1, acc, 0, 0, 0);
            float bias = qb[nt * 16 + lo];
            if (nt < 8) {
#pragma unroll
                for (int r = 0; r < 4; r++) qkb[quad * 4 + r][nt * 16 + lo] = f2bu(acc[r] + bias);
            } else {
#pragma unroll
                for (int r = 0; r < 4; r++) vt[(nt - 8) * 16 + lo][quad * 4 + r] = f2bu(acc[r] + bias);
            }
        }

        short8 zf = {0, 0, 0, 0, 0, 0, 0, 0};
        // scores: q consumed per head, P overwrites q's columns (0-63)
#pragma unroll
        for (int h = 0; h < 4; h++) {
            short8 qf = zf, kf = zf;
            if (quad < 2) {
                qf = *(const short8*)&qkb[lo][h * 16 + quad * 8];
                kf = *(const short8*)&qkb[lo][64 + h * 16 + quad * 8];
            }
            f32x4 s4 = {0.f, 0.f, 0.f, 0.f};
            s4 = __builtin_amdgcn_mfma_f32_16x16x32_bf16(qf, kf, s4, 0, 0, 0);
#pragma unroll
            for (int r = 0; r < 4; r++) {
                float sv = s4[r] * 0.25f + adjr[r];
                float mx = sv;
                mx = fmaxf(mx, __shfl_xor(mx, 1));
                mx = fmaxf(mx, __shfl_xor(mx, 2));
                mx = fmaxf(mx, __shfl_xor(mx, 4));
                mx = fmaxf(mx, __shfl_xor(mx, 8));
                float e = __expf(sv - mx);
                float sm = e;
                sm += __shfl_xor(sm, 1);
                sm += __shfl_xor(sm, 2);
                sm += __shfl_xor(sm, 4);
                sm += __shfl_xor(sm, 8);
                qkb[quad * 4 + r][h * 16 + lo] = f2bu(e / sm);
            }
        }
        // PV: P consumed per head, O overwrites P's columns (0-63)
#pragma unroll
        for (int h = 0; h < 4; h++) {
            short8 pf = zf, vf = zf;
            if (quad < 2) {
                pf = *(const short8*)&qkb[lo][h * 16 + quad * 8];
                vf = *(const short8*)&vt[h * 16 + lo][quad * 8];
            }
            f32x4 oc = {0.f, 0.f, 0.f, 0.f};
            oc = __builtin_amdgcn_mfma_f32_16x16x32_bf16(pf, vf, oc, 0, 0, 0);
#pragma unroll
            for (int r = 0; r < 4; r++) qkb[quad * 4 + r][h * 16 + lo] = f2bu(oc[r]);
        }
        short8 pa0 = *(const short8*)&qkb[lo][quad * 8];
        short8 pa1 = *(const short8*)&qkb[lo][32 + quad * 8];
#pragma unroll
        for (int nt = 0; nt < 4; nt++) {
            const ushort_t* wr = wo + (nt * 16 + lo) * 64 + quad * 8;
            short8 b0 = *(const short8*)wr;
            short8 b1 = *(const short8*)(wr + 32);
            f32x4 acc = {0.f, 0.f, 0.f, 0.f};
            acc = __builtin_amdgcn_mfma_f32_16x16x32_bf16(pa0, b0, acc, 0, 0, 0);
            acc = __builtin_amdgcn_mfma_f32_16x16x32_bf16(pa1, b1, acc, 0, 0, 0);
            float bias = ob[nt * 16 + lo];
#pragma unroll
            for (int r = 0; r < 4; r++) htw[quad * 4 + r][nt * 16 + lo] += acc[r] + bias;
        }
        short8 fa0, fa1;
        ln_frag(htw, n2g_ + layer * 64, n2b_ + layer * 64, quad, lo, fa0, fa1);
#pragma unroll
        for (int nt = 0; nt < 8; nt++) {
            const ushort_t* wr = wf1 + (nt * 16 + lo) * 64 + quad * 8;
            short8 b0 = *(const short8*)wr;
            short8 b1 = *(const short8*)(wr + 32);
            f32x4 acc = {0.f, 0.f, 0.f, 0.f};
            acc = __builtin_amdgcn_mfma_f32_16x16x32_bf16(fa0, b0, acc, 0, 0, 0);
            acc = __builtin_amdgcn_mfma_f32_16x16x32_bf16(fa1, b1, acc, 0, 0, 0);
            float bias = f1b[nt * 16 + lo];
#pragma unroll
            for (int r = 0; r < 4; r++) qkb[quad * 4 + r][nt * 16 + lo] = f2bu(geluf(acc[r] + bias));
        }
        short8 ga[4];
#pragma unroll
        for (int kb = 0; kb < 4; kb++) ga[kb] = *(const short8*)&qkb[lo][kb * 32 + quad * 8];
#pragma unroll
        for (int nt = 0; nt < 4; nt++) {
            const ushort_t* wr = wf2 + (nt * 16 + lo) * 128 + quad * 8;
            f32x4 acc = {0.f, 0.f, 0.f, 0.f};
#pragma unroll
            for (int kb = 0; kb < 4; kb++) {
                short8 bb = *(const short8*)(wr + kb * 32);
                acc = __builtin_amdgcn_mfma_f32_16x16x32_bf16(ga[kb], bb, acc, 0, 0, 0);
            }
            float bias = f2b[nt * 16 + lo];
#pragma unroll
            for (int r = 0; r < 4; r++) htw[quad * 4 + r][nt * 16 + lo] += acc[r] + bias;
        }
    }
    // ---- final LN -> bf16 hmb (same per-lane column ownership) ----
    {
        float v[16];
        const float4* r0 = (const float4*)(&htw[lo][quad * 8]);
        const float4* r1 = (const float4*)(&htw[lo][32 + quad * 8]);
        float4 p0 = r0[0], p1 = r0[1], p2 = r1[0], p3 = r1[1];
        v[0] = p0.x; v[1] = p0.y; v[2] = p0.z; v[3] = p0.w;
        v[4] = p1.x; v[5] = p1.y; v[6] = p1.z; v[7] = p1.w;
        v[8] = p2.x; v[9] = p2.y; v[10] = p2.z; v[11] = p2.w;
        v[12] = p3.x; v[13] = p3.y; v[14] = p3.z; v[15] = p3.w;
        float s = 0.f;
#pragma unroll
        for (int i = 0; i < 16; i++) s += v[i];
        s += __shfl_xor(s, 16); s += __shfl_xor(s, 32);
        float mean = s * (1.0f / 64.0f);
        float q = 0.f;
#pragma unroll
        for (int i = 0; i < 16; i++) { float d = v[i] - mean; q += d * d; }
        q += __shfl_xor(q, 16); q += __shfl_xor(q, 32);
        float rstd = rsqrtf(q * (1.0f / 64.0f) + 1e-5f);
        float4 g0 = *(const float4*)(gng + quad * 8);
        float4 g1 = *(const float4*)(gng + quad * 8 + 4);
        float4 g2 = *(const float4*)(gng + 32 + quad * 8);
        float4 g3 = *(const float4*)(gng + 32 + quad * 8 + 4);
        float4 b0 = *(const float4*)(gnb + quad * 8);
        float4 b1 = *(const float4*)(gnb + quad * 8 + 4);
        float4 b2 = *(const float4*)(gnb + 32 + quad * 8);
        float4 b3 = *(const float4*)(gnb + 32 + quad * 8 + 4);
        float gg[16] = {g0.x, g0.y, g0.z, g0.w, g1.x, g1.y, g1.z, g1.w,
                        g2.x, g2.y, g2.z, g2.w, g3.x, g3.y, g3.z, g3.w};
        float bb[16] = {b0.x, b0.y, b0.z, b0.w, b1.x, b1.y, b1.z, b1.w,
                        b2.x, b2.y, b2.z, b2.w, b3.x, b3.y, b3.z, b3.w};
        unsigned u[8];
#pragma unroll
        for (int i = 0; i < 4; i++) {
            float oa = (v[2 * i] - mean) * rstd * gg[2 * i] + bb[2 * i];
            float obv = (v[2 * i + 1] - mean) * rstd * gg[2 * i + 1] + bb[2 * i + 1];
            u[i] = pack2bf(oa, obv);
            float oc = (v[8 + 2 * i] - mean) * rstd * gg[8 + 2 * i] + bb[8 + 2 * i];
            float od = (v[9 + 2 * i] - mean) * rstd * gg[9 + 2 * i] + bb[9 + 2 * i];
            u[4 + i] = pack2bf(oc, od);
        }
        ushort_t* dst = hmb + (size_t)(b * 16 + lo) * 16384 + (size_t)tp * 64;
        *(uint4*)(dst + quad * 8) = make_uint4(u[0], u[1], u[2], u[3]);
        *(uint4*)(dst + 32 + quad * 8) = make_uint4(u[4], u[5], u[6], u[7]);
    }
}

// =============================== K6: GRU (MFMA, W-as-A) ======================
__global__ __launch_bounds__(256) void k_gru(
    const ushort_t* __restrict__ hmb, const ushort_t* __restrict__ wgru,
    const float* __restrict__ bih_, const float* __restrict__ bhh_,
    float* __restrict__ h_out)
{
    __shared__ ushort_t hbuf[2][16][72];
    int t = threadIdx.x;
    int w = t >> 6, l = t & 63;
    int lo = l & 15, qd = l >> 4;
    int dir = blockIdx.x >> 5;
    int cseq0 = (blockIdx.x & 31) * 16;
    const ushort_t* wih = wgru + dir * 12288;
    const ushort_t* whh = wgru + 24576 + dir * 12288;
    const ushort_t* pr0 = wih + ((w) * 16 + lo) * 64 + qd * 8;
    const ushort_t* pz0 = wih + ((4 + w) * 16 + lo) * 64 + qd * 8;
    const ushort_t* pn0 = wih + ((8 + w) * 16 + lo) * 64 + qd * 8;
    const ushort_t* hr0 = whh + ((w) * 16 + lo) * 64 + qd * 8;
    const ushort_t* hz0 = whh + ((4 + w) * 16 + lo) * 64 + qd * 8;
    const ushort_t* hn0 = whh + ((8 + w) * 16 + lo) * 64 + qd * 8;
    short8 wi_r0 = *(const short8*)pr0, wi_r1 = *(const short8*)(pr0 + 32);
    short8 wi_z0 = *(const short8*)pz0, wi_z1 = *(const short8*)(pz0 + 32);
    short8 wi_n0 = *(const short8*)pn0, wi_n1 = *(const short8*)(pn0 + 32);
    short8 wh_r0 = *(const short8*)hr0, wh_r1 = *(const short8*)(hr0 + 32);
    short8 wh_z0 = *(const short8*)hz0, wh_z1 = *(const short8*)(hz0 + 32);
    short8 wh_n0 = *(const short8*)hn0, wh_n1 = *(const short8*)(hn0 + 32);
    int d_base = w * 16 + qd * 4;
    float bsr[4], bsz[4], bin[4], bhn[4];
#pragma unroll
    for (int r = 0; r < 4; r++) {
        bsr[r] = bih_[dir * 192 + d_base + r] + bhh_[dir * 192 + d_base + r];
        bsz[r] = bih_[dir * 192 + 64 + d_base + r] + bhh_[dir * 192 + 64 + d_base + r];
        bin[r] = bih_[dir * 192 + 128 + d_base + r];
        bhn[r] = bhh_[dir * 192 + 128 + d_base + r];
    }
    const ushort_t* xrow = hmb + (size_t)(cseq0 + lo) * 16384 + qd * 8;
    for (int i = t; i < 2 * 16 * 72; i += 256) ((ushort_t*)hbuf)[i] = 0;
    float h_old[4] = {0.f, 0.f, 0.f, 0.f};

    int s0 = dir ? 255 : 0;
    int s1 = dir ? 254 : 1;
    int s2 = dir ? 253 : 2;
    short8 xc0 = *(const short8*)(xrow + s0 * 64);
    short8 xc1 = *(const short8*)(xrow + s0 * 64 + 32);
    short8 xA0 = *(const short8*)(xrow + s1 * 64);
    short8 xA1 = *(const short8*)(xrow + s1 * 64 + 32);
    short8 xB0 = *(const short8*)(xrow + s2 * 64);
    short8 xB1 = *(const short8*)(xrow + s2 * 64 + 32);
    f32x4 axr = {0.f, 0.f, 0.f, 0.f}, axz = {0.f, 0.f, 0.f, 0.f}, axn = {0.f, 0.f, 0.f, 0.f};
    axr = __builtin_amdgcn_mfma_f32_16x16x32_bf16(wi_r0, xc0, axr, 0, 0, 0);
    axr = __builtin_amdgcn_mfma_f32_16x16x32_bf16(wi_r1, xc1, axr, 0, 0, 0);
    axz = __builtin_amdgcn_mfma_f32_16x16x32_bf16(wi_z0, xc0, axz, 0, 0, 0);
    axz = __builtin_amdgcn_mfma_f32_16x16x32_bf16(wi_z1, xc1, axz, 0, 0, 0);
    axn = __builtin_amdgcn_mfma_f32_16x16x32_bf16(wi_n0, xc0, axn, 0, 0, 0);
    axn = __builtin_amdgcn_mfma_f32_16x16x32_bf16(wi_n1, xc1, axn, 0, 0, 0);
    __syncthreads();
#pragma unroll 2
    for (int step = 0; step < 256; step++) {
        int cur = step & 1, nxt = cur ^ 1;
        f32x4 nxr = {0.f, 0.f, 0.f, 0.f}, nxz = {0.f, 0.f, 0.f, 0.f}, nxn = {0.f, 0.f, 0.f, 0.f};
        nxr = __builtin_amdgcn_mfma_f32_16x16x32_bf16(wi_r0, xA0, nxr, 0, 0, 0);
        nxr = __builtin_amdgcn_mfma_f32_16x16x32_bf16(wi_r1, xA1, nxr, 0, 0, 0);
        nxz = __builtin_amdgcn_mfma_f32_16x16x32_bf16(wi_z0, xA0, nxz, 0, 0, 0);
        nxz = __builtin_amdgcn_mfma_f32_16x16x32_bf16(wi_z1, xA1, nxz, 0, 0, 0);
        nxn = __builtin_amdgcn_mfma_f32_16x16x32_bf16(wi_n0, xA0, nxn, 0, 0, 0);
        nxn = __builtin_amdgcn_mfma_f32_16x16x32_bf16(wi_n1, xA1, nxn, 0, 0, 0);
        xA0 = xB0; xA1 = xB1;
        int tl = step + 3 > 255 ? 255 : step + 3;
        int sf = dir ? 255 - tl : tl;
        xB0 = *(const short8*)(xrow + sf * 64);
        xB1 = *(const short8*)(xrow + sf * 64 + 32);
        short8 bh0 = *(const short8*)&hbuf[cur][lo][qd * 8];
        short8 bh1 = *(const short8*)&hbuf[cur][lo][32 + qd * 8];
        f32x4 ar = axr, az = axz;
        f32x4 anh = {0.f, 0.f, 0.f, 0.f};
        ar = __builtin_amdgcn_mfma_f32_16x16x32_bf16(wh_r0, bh0, ar, 0, 0, 0);
        ar = __builtin_amdgcn_mfma_f32_16x16x32_bf16(wh_r1, bh1, ar, 0, 0, 0);
        az = __builtin_amdgcn_mfma_f32_16x16x32_bf16(wh_z0, bh0, az, 0, 0, 0);
        az = __builtin_amdgcn_mfma_f32_16x16x32_bf16(wh_z1, bh1, az, 0, 0, 0);
        anh = __builtin_amdgcn_mfma_f32_16x16x32_bf16(wh_n0, bh0, anh, 0, 0, 0);
        anh = __builtin_amdgcn_mfma_f32_16x16x32_bf16(wh_n1, bh1, anh, 0, 0, 0);
        float hv[4];
#pragma unroll
        for (int r = 0; r < 4; r++) {
            float gr = sigmoidf_(ar[r] + bsr[r]);
            float gz = sigmoidf_(az[r] + bsz[r]);
            float nin = (axn[r] + bin[r]) + gr * (anh[r] + bhn[r]);
            nin = fminf(fmaxf(nin, -15.f), 15.f);
            float e = __expf(-2.f * nin);
            float gn = (1.f - e) / (1.f + e);
            float hn = gn + gz * (h_old[r] - gn);
            h_old[r] = hn;
            hv[r] = hn;
        }
        *(uint2*)&hbuf[nxt][lo][d_base] = make_uint2(pack2bf(hv[0], hv[1]), pack2bf(hv[2], hv[3]));
        asm volatile("s_waitcnt lgkmcnt(0)\n\ts_barrier" ::: "memory");
        axr = nxr; axz = nxz; axn = nxn;
    }
    *(float4*)&h_out[(size_t)(cseq0 + lo) * 128 + dir * 64 + d_base] =
        make_float4(h_old[0], h_old[1], h_old[2], h_old[3]);
}

// =============================== K7: readout =================================
__global__ __launch_bounds__(128) void k_readout(
    const float* __restrict__ h_out, const float* __restrict__ gw, const float* __restrict__ gb,
    void* __restrict__ out, const int* __restrict__ flag)
{
    __shared__ float gate_s[16];
    __shared__ float gws[128];
    int b = blockIdx.x, t = threadIdx.x;
    gws[t] = gw[t];
    __syncthreads();
    int isb = *flag;
    if (t < 16) {
        const float* hr = h_out + (size_t)(b * 16 + t) * 128;
        float acc = gb[0];
        for (int k = 0; k < 128; k++) acc += hr[k] * gws[k];
        float g = sigmoidf_(acc);
        gate_s[t] = g;
        if (isb) ((bf16*)out)[12288 + b * 16 + t] = f2b(g);
        else     ((float*)out)[12288 + b * 16 + t] = g;
    }
    __syncthreads();
    float den = 1e-8f;
#pragma unroll
    for (int c = 0; c < 16; c++) den += gate_s[c];
    float num = 0.f;
#pragma unroll
    for (int c = 0; c < 16; c++) num += h_out[(size_t)(b * 16 + c) * 128 + t] * gate_s[c];
    float v = num / den;
    if (isb) ((bf16*)out)[b * 128 + t] = f2b(v);
    else     ((float*)out)[b * 128 + t] = v;
}

// =============================== launch ======================================
extern "C" void kernel_launch(void* const* d_in, const int* in_sizes, int n_in,
                              void* d_out, int out_size, void* d_ws, size_t ws_size,
                              hipStream_t stream)
{
    int* flag = (int*)d_ws;
    float* cvt = (float*)((char*)d_ws + 256);

    InPtrs P;
    InOffs O;
    int cum = 0;
    for (int i = 0; i < 35; i++) {
        P.p[i] = d_in[i];
        O.off[i] = cum;
        O.sz[i] = in_sizes[i];
        cum += (in_sizes[i] + 7) & ~7;
    }
    int total = cum;

    const float* x     = cvt + O.off[0];
    const float* c1w   = cvt + O.off[1];
    const float* c1b   = cvt + O.off[2];
    const float* bn1g  = cvt + O.off[3];
    const float* bn1b  = cvt + O.off[4];
    const float* bn1m  = cvt + O.off[5];
    const float* bn1v  = cvt + O.off[6];
    const float* c2w   = cvt + O.off[7];
    const float* c2b   = cvt + O.off[8];
    const float* bn2g  = cvt + O.off[9];
    const float* bn2b  = cvt + O.off[10];
    const float* bn2m  = cvt + O.off[11];
    const float* bn2v  = cvt + O.off[12];
    const float* prior = cvt + O.off[13];
    const float* logw  = cvt + O.off[14];
    const float* n1g   = cvt + O.off[15];
    const float* n1b   = cvt + O.off[16];
    const float* qkvw  = cvt + O.off[17];
    const float* qkvb  = cvt + O.off[18];
    const float* outw  = cvt + O.off[19];
    const float* outb  = cvt + O.off[20];
    const float* n2g   = cvt + O.off[21];
    const float* n2b   = cvt + O.off[22];
    const float* f1w   = cvt + O.off[23];
    const float* f1b   = cvt + O.off[24];
    const float* f2w   = cvt + O.off[25];
    const float* f2b_  = cvt + O.off[26];
    const float* gng   = cvt + O.off[27];
    const float* gnb   = cvt + O.off[28];
    const float* gwih  = cvt + O.off[29];
    const float* gwhh  = cvt + O.off[30];
    const float* gbih  = cvt + O.off[31];
    const float* gbhh  = cvt + O.off[32];
    const float* gatew = cvt + O.off[33];
    const float* gateb = cvt + O.off[34];

    float* fbase = cvt + ((total + 63) & ~63);
    float* hm    = fbase;                              // 8388608 floats (CNN out)
    ushort_t* Xnb = (ushort_t*)(hm + 8388608);         // 512*2080 bf16 spectrum
    float* hnf   = fbase + 8921088;                    // 32768
    float* adjw  = hnf + 32768;                        // 8192
    float* hout  = adjw + 8192;                        // 65536
    unsigned* wpk = (unsigned*)(hout + 65536);         // 62464 uints (bf16 weights)
    ushort_t* hmb = (ushort_t*)(wpk + 62464);          // 8388608 bf16 (GAT out)

    k_detect<<<1, 256, 0, stream>>>((const unsigned*)d_in[0], flag);
    k_convert<<<(total + 255) / 256, 256, 0, stream>>>(P, O, total, flag, cvt);
    k_pack<<<244, 256, 0, stream>>>(qkvw, outw, f1w, f2w, gwih, gwhh, c2w, wpk);
    k_front<<<768, 256, 0, stream>>>(x, c1w, c1b, bn1g, bn1b, bn1m, bn1v,
                                     c2b, bn2g, bn2b, bn2m, bn2v,
                                     (const ushort_t*)(wpk + 57344), hm, Xnb, hnf);
    k_adj<<<32, 256, 0, stream>>>(Xnb, hnf, prior, logw, adjw, d_out, flag);
    k_gat<<<2048, 256, 0, stream>>>(hm, adjw, (const ushort_t*)wpk,
                                    qkvb, outb, f1b, f2b_, n1g, n1b, n2g, n2b, gng, gnb, hmb);
    k_gru<<<64, 256, 0, stream>>>(hmb, (const ushort_t*)(wpk + 32768), gbih, gbhh, hout);
    k_readout<<<32, 128, 0, stream>>>(hout, gatew, gateb, d_out, flag);
}

// Round 11
// 561.461 us; speedup vs baseline: 1.0758x; 1.0758x over previous
//
#include <hip/hip_runtime.h>
#include <hip/hip_bf16.h>
#include <math.h>

typedef __hip_bfloat16 bf16;
typedef unsigned short ushort_t;
typedef __attribute__((ext_vector_type(8))) short short8;
typedef __attribute__((ext_vector_type(4))) float f32x4;

__device__ __forceinline__ float b2f(bf16 v) { return __bfloat162float(v); }
__device__ __forceinline__ bf16 f2b(float v) { return __float2bfloat16(v); }
__device__ __forceinline__ float sigmoidf_(float x) { return 1.0f / (1.0f + __expf(-x)); }

// fast exact-gelu: erf via Abramowitz-Stegun 7.1.26 (|err| <= 1.5e-7)
__device__ __forceinline__ float geluf(float x) {
    float z = x * 0.70710678118654752f;
    float az = fabsf(z);
    float t = 1.0f / (1.0f + 0.3275911f * az);
    float poly = ((((1.061405429f * t - 1.453152027f) * t + 1.421413741f) * t
                   - 0.284496736f) * t + 0.254829592f) * t;
    float erfa = 1.0f - poly * __expf(-z * z);
    float er = (z < 0.f) ? -erfa : erfa;
    return 0.5f * x * (1.0f + er);
}

__device__ __forceinline__ unsigned pack2bf(float a, float b) {
    unsigned ua = __float_as_uint(a); ua = (ua + 0x7FFFu + ((ua >> 16) & 1u)) >> 16;
    unsigned ub = __float_as_uint(b); ub = (ub + 0x7FFFu + ((ub >> 16) & 1u)) >> 16;
    return ua | (ub << 16);
}
__device__ __forceinline__ ushort_t f2bu(float v) {
    unsigned u = __float_as_uint(v);
    u = (u + 0x7FFFu + ((u >> 16) & 1u)) >> 16;
    return (ushort_t)u;
}

// ========================== K0a: dtype detector ==============================
__global__ __launch_bounds__(256) void k_detect(const unsigned* __restrict__ x, int* __restrict__ flag)
{
    __shared__ int cnt;
    if (threadIdx.x == 0) cnt = 0;
    __syncthreads();
    unsigned u = x[threadIdx.x] & 0xFFFFu;
    float f = __uint_as_float(u << 16);
    float a = fabsf(f);
    int sane = (f == 0.0f) || (a > 1e-8f && a < 1e4f);
    atomicAdd(&cnt, sane);
    __syncthreads();
    if (threadIdx.x == 0) *flag = (cnt >= 160) ? 1 : 0;
}

// ========================== K0b: canonicalize to fp32 ========================
struct InPtrs { const void* p[35]; };
struct InOffs { int off[35]; int sz[35]; };

__global__ __launch_bounds__(256) void k_convert(InPtrs P, InOffs O, int total,
                                                 const int* __restrict__ flag,
                                                 float* __restrict__ cvt)
{
    int idx = blockIdx.x * 256 + threadIdx.x;
    if (idx >= total) return;
    int isb = *flag;
    float v = 0.f;
    if (idx < O.sz[0]) {
        // fast path: segment 0 (x) is ~94% of all elements
        v = isb ? b2f(((const bf16*)P.p[0])[idx]) : ((const float*)P.p[0])[idx];
    } else {
#pragma unroll 1
        for (int s = 1; s < 35; s++) {
            int rel = idx - O.off[s];
            if (rel >= 0 && rel < O.sz[s]) {
                v = isb ? b2f(((const bf16*)P.p[s])[rel]) : ((const float*)P.p[s])[rel];
                break;
            }
        }
    }
    cvt[idx] = v;
}

// ========================== K0c: pack weights to bf16 ========================
// uint regions: qw 12288 | ow 4096 | f1w 8192 | f2w 8192 | gwih 12288 | gwhh 12288
//             | conv2 wt [tap][d][ic] 5120
__global__ __launch_bounds__(256) void k_pack(const float* __restrict__ qw, const float* __restrict__ ow,
                                              const float* __restrict__ f1w, const float* __restrict__ f2w,
                                              const float* __restrict__ gwih, const float* __restrict__ gwhh,
                                              const float* __restrict__ c2w,
                                              unsigned* __restrict__ dst)
{
    int i = blockIdx.x * 256 + threadIdx.x;
    if (i >= 62464) return;
    if (i >= 57344) {
        int j0 = (i - 57344) * 2;
        int tap = j0 >> 11, rem = j0 & 2047;
        int d = rem >> 5, ic = rem & 31;
        dst[i] = pack2bf(c2w[d * 160 + ic * 5 + tap], c2w[d * 160 + (ic + 1) * 5 + tap]);
        return;
    }
    const float* s; int rel;
    if (i < 12288)      { s = qw;   rel = i; }
    else if (i < 16384) { s = ow;   rel = i - 12288; }
    else if (i < 24576) { s = f1w;  rel = i - 16384; }
    else if (i < 32768) { s = f2w;  rel = i - 24576; }
    else if (i < 45056) { s = gwih; rel = i - 32768; }
    else                { s = gwhh; rel = i - 45056; }
    dst[i] = pack2bf(s[2 * rel], s[2 * rel + 1]);
}

// ====================== K1: fused front (CNN+havg | pair-FFT) ================
__global__ __launch_bounds__(256) void k_front(
    const float* __restrict__ x,
    const float* __restrict__ c1w, const float* __restrict__ c1b,
    const float* __restrict__ bn1g, const float* __restrict__ bn1b, const float* __restrict__ bn1m, const float* __restrict__ bn1v,
    const float* __restrict__ c2b,
    const float* __restrict__ bn2g, const float* __restrict__ bn2b, const float* __restrict__ bn2m, const float* __restrict__ bn2v,
    const ushort_t* __restrict__ w2pk,
    float* __restrict__ h_main, ushort_t* __restrict__ Xnb, float* __restrict__ hnf)
{
    __shared__ float smem[9984];
    int t = threadIdx.x;
    if (blockIdx.x >= 512) {
        // ---------------- pair-FFT path ----------------
        float* re = smem;
        float* im = smem + 4096;
        float* red = smem + 8192;
        int bc2 = blockIdx.x - 512;            // 0..255
        int b = bc2 >> 3, cp = bc2 & 7;
        const float* xa = x + ((size_t)b * 16 + 2 * cp) * 4096;
        const float* xb = xa + 4096;
        for (int i = t; i < 4096; i += 256) {
            int r = __brev((unsigned)i) >> 20;
            re[r] = xa[i];
            im[r] = xb[i];
        }
        __syncthreads();
        for (int s = 1; s <= 12; s++) {
            int half = 1 << (s - 1);
            float ang = -6.283185307179586f / (float)(1 << s);
            for (int m = t; m < 2048; m += 256) {
                int j = m & (half - 1);
                int pos = ((m >> (s - 1)) << s) | j;
                float sn, cs;
                __sincosf(ang * (float)j, &sn, &cs);
                float ur = re[pos], ui = im[pos];
                float vr = re[pos + half], vi = im[pos + half];
                float tr = vr * cs - vi * sn;
                float ti = vr * sn + vi * cs;
                re[pos] = ur + tr; im[pos] = ui + ti;
                re[pos + half] = ur - tr; im[pos + half] = ui - ti;
            }
            __syncthreads();
        }
        float maga[9], magb[9];
        float ssa = 0.f, ssb = 0.f;
#pragma unroll
        for (int it = 0; it < 9; it++) {
            int k = t + it * 256;
            float ma = 0.f, mb = 0.f;
            if (k <= 2048) {
                int kn = (4096 - k) & 4095;
                float Rk = re[k], Ik = im[k], Rn = re[kn], In = im[kn];
                float ra = 0.5f * (Rk + Rn), ia = 0.5f * (Ik - In);
                float rb = 0.5f * (Ik + In), ib = 0.5f * (Rn - Rk);
                ma = sqrtf(ra * ra + ia * ia);
                mb = sqrtf(rb * rb + ib * ib);
                ssa += ma * ma; ssb += mb * mb;
            }
            maga[it] = ma; magb[it] = mb;
        }
        for (int off = 32; off; off >>= 1) { ssa += __shfl_xor(ssa, off, 64); ssb += __shfl_xor(ssb, off, 64); }
        int w = t >> 6;
        if ((t & 63) == 0) { red[w] = ssa; red[4 + w] = ssb; }
        __syncthreads();
        float inva = 1.0f / (sqrtf(red[0] + red[1] + red[2] + red[3]) + 1e-8f);
        float invb = 1.0f / (sqrtf(red[4] + red[5] + red[6] + red[7]) + 1e-8f);
        ushort_t* rowa = Xnb + ((size_t)b * 16 + 2 * cp) * 2080;
        ushort_t* rowb = rowa + 2080;
#pragma unroll
        for (int it = 0; it < 9; it++) {
            int k = t + it * 256;
            if (k <= 2048) {
                rowa[k] = f2bu(maga[it] * inva);
                rowb[k] = f2bu(magb[it] * invb);
            }
        }
        for (int f = 2049 + t; f < 2080; f += 256) { rowa[f] = 0; rowb[f] = 0; }
        return;
    }
    // ---------------- CNN path ----------------
    float* ubuf = smem;                           // 4352 floats
    ushort_t* h1t = (ushort_t*)(smem + 4352);     // 10400 ushorts (260 rows x 40)
    float* A2s = smem + 9552;
    float* B2s = smem + 9616;
    float* hsum = smem + 9680;                    // 256
    int bc = blockIdx.x;
    int l = t & 63, w = t >> 6;
    int lo = l & 15, quad = l >> 4;

    if (t < 64) {
        float s = bn2g[t] * rsqrtf(bn2v[t] + 1e-5f);
        A2s[t] = s; B2s[t] = (c2b[t] - bn2m[t]) * s + bn2b[t];
    }
    int icp = t & 15;
    float w1r[2][7], A1r[2], B1r[2];
#pragma unroll
    for (int s = 0; s < 2; s++) {
        int ic = icp * 2 + s;
#pragma unroll
        for (int k = 0; k < 7; k++) w1r[s][k] = c1w[ic * 7 + k];
        float sc = bn1g[ic] * rsqrtf(bn1v[ic] + 1e-5f);
        A1r[s] = sc; B1r[s] = (c1b[ic] - bn1m[ic]) * sc + bn1b[ic];
    }
    short8 Afr[4][5];
#pragma unroll
    for (int dt = 0; dt < 4; dt++)
#pragma unroll
        for (int tap = 0; tap < 5; tap++)
            Afr[dt][tap] = *(const short8*)(w2pk + ((tap * 64 + dt * 16 + lo) * 32 + quad * 8));

    const float* xrow = x + (size_t)bc * 4096;
    float rs = 0.f;
    int dd = t & 63, pg = t >> 6;
    int rsel = lo & 3;
    for (int tile = 0; tile < 4; tile++) {
        int X0 = 1024 * tile - 11;
        for (int i = t; i < 1056; i += 256) {
            int g = X0 + i;
            ubuf[i] = (g >= 0 && g < 4096) ? xrow[g] : 0.0f;
        }
        __syncthreads();
        for (int pos = (t >> 4); pos < 260; pos += 16) {
            const float4* xw = (const float4*)&ubuf[4 * pos];
            float4 fa = xw[0], fb = xw[1], fc = xw[2];
            float xv[12] = {fa.x, fa.y, fa.z, fa.w, fb.x, fb.y, fb.z, fb.w,
                            fc.x, fc.y, fc.z, fc.w};
            int t1pg = tile * 256 + pos - 2;
            bool ok = (t1pg >= 0 && t1pg < 1024);
            float res[2];
#pragma unroll
            for (int s = 0; s < 2; s++) {
                float a0 = 0.f, a1 = 0.f, a2 = 0.f, a3 = 0.f;
#pragma unroll
                for (int k = 0; k < 7; k++) {
                    float wv = w1r[s][k];
                    a0 += xv[k] * wv;     a1 += xv[k + 1] * wv;
                    a2 += xv[k + 2] * wv; a3 += xv[k + 3] * wv;
                }
                float A = A1r[s], B = B1r[s];
                a0 = a0 * A + B; a1 = a1 * A + B; a2 = a2 * A + B; a3 = a3 * A + B;
                float mx = fmaxf(fmaxf(a0, a1), fmaxf(a2, a3));
                float mn = fminf(fminf(a0, a1), fminf(a2, a3));
                res[s] = ok ? fmaxf(geluf(mx), geluf(mn)) : 0.0f;
            }
            ((unsigned*)h1t)[pos * 20 + icp] = pack2bf(res[0], res[1]);
        }
        __syncthreads();
        float* houtile = ubuf;
#pragma unroll
        for (int ni = 0; ni < 4; ni++) {
            int nt = w * 4 + ni;
            short8 bfr[5];
#pragma unroll
            for (int tap = 0; tap < 5; tap++)
                bfr[tap] = *(const short8*)&h1t[(nt * 16 + lo + tap) * 40 + quad * 8];
#pragma unroll
            for (int dt = 0; dt < 4; dt++) {
                f32x4 acc = {0.f, 0.f, 0.f, 0.f};
#pragma unroll
                for (int tap = 0; tap < 5; tap++)
                    acc = __builtin_amdgcn_mfma_f32_16x16x32_bf16(Afr[dt][tap], bfr[tap], acc, 0, 0, 0);
                const float4 a2 = *(const float4*)&A2s[dt * 16 + quad * 4];
                const float4 b2 = *(const float4*)&B2s[dt * 16 + quad * 4];
                float a2a[4] = {a2.x, a2.y, a2.z, a2.w};
                float b2a[4] = {b2.x, b2.y, b2.z, b2.w};
                // butterfly leaves group min/max on ALL 4 lanes; lane rsel=lo&3
                // owns output r==rsel -> gelus deduped 4x (exact same values).
                float mnr = 0.f, mxr = 0.f;
#pragma unroll
                for (int r = 0; r < 4; r++) {
                    float v = acc[r] * a2a[r] + b2a[r];
                    float o1 = __shfl_xor(v, 1);
                    float mx = fmaxf(v, o1), mn = fminf(v, o1);
                    float mx2 = __shfl_xor(mx, 2), mn2 = __shfl_xor(mn, 2);
                    mx = fmaxf(mx, mx2); mn = fminf(mn, mn2);
                    if (rsel == r) { mnr = mn; mxr = mx; }
                }
                float res = fmaxf(geluf(mxr), geluf(mnr));
                houtile[(nt * 4 + (lo >> 2)) * 68 + dt * 16 + quad * 4 + rsel] = res;
            }
        }
        __syncthreads();
#pragma unroll
        for (int i = 0; i < 16; i++) rs += ubuf[(pg * 16 + i) * 68 + dd];
        float* dst = h_main + (size_t)bc * 16384 + tile * 4096;
        for (int i = t * 4; i < 4096; i += 1024) {
            float4 v = *(const float4*)&ubuf[(i >> 6) * 68 + (i & 63)];
            *(float4*)&dst[i] = v;
        }
        __syncthreads();
    }
    hsum[t] = rs;
    __syncthreads();
    if (t < 64) {
        float avg = (hsum[t] + hsum[64 + t] + hsum[128 + t] + hsum[192 + t]) * (1.0f / 256.0f);
        float tot = avg;
        for (int off = 32; off; off >>= 1) tot += __shfl_xor(tot, off, 64);
        float hc = avg - tot * (1.0f / 64.0f);
        float sq = hc * hc;
        for (int off = 32; off; off >>= 1) sq += __shfl_xor(sq, off, 64);
        hnf[bc * 64 + t] = hc / (sqrtf(sq) + 1e-8f);
    }
}

// =============================== K4: adjacency (MFMA) ========================
__global__ __launch_bounds__(256) void k_adj(
    const ushort_t* __restrict__ Xnb, const float* __restrict__ hnf,
    const float* __restrict__ prior, const float* __restrict__ logw,
    float* __restrict__ adjw, void* __restrict__ out, const int* __restrict__ flag)
{
    __shared__ float tile[4][16][17];
    __shared__ float hh[1024];
    int b = blockIdx.x, t = threadIdx.x;
    int w = t >> 6, l = t & 63;
    int lo = l & 15, quad = l >> 4;
    for (int i = t; i < 1024; i += 256) hh[i] = hnf[b * 1024 + i];
    const ushort_t* base = Xnb + (size_t)b * 16 * 2080 + lo * 2080 + quad * 8;
    f32x4 acc = {0.f, 0.f, 0.f, 0.f};
    for (int kb = w; kb < 65; kb += 4) {
        short8 f = *(const short8*)(base + kb * 32);
        acc = __builtin_amdgcn_mfma_f32_16x16x32_bf16(f, f, acc, 0, 0, 0);
    }
#pragma unroll
    for (int r = 0; r < 4; r++) tile[w][quad * 4 + r][lo] = acc[r];
    __syncthreads();
    int c = t >> 4, e = t & 15;
    float sc = tile[0][c][e] + tile[1][c][e] + tile[2][c][e] + tile[3][c][e];
    float fc = 0.f;
#pragma unroll
    for (int d = 0; d < 64; d++) fc += hh[c * 64 + d] * hh[e * 64 + d];
    float l0 = logw[0], l1 = logw[1], l2 = logw[2];
    float mx = fmaxf(l0, fmaxf(l1, l2));
    float e0 = __expf(l0 - mx), e1 = __expf(l1 - mx), e2 = __expf(l2 - mx);
    float isum = 1.0f / (e0 + e1 + e2);
    float pr = prior[c * 16 + e] + prior[e * 16 + c];
    float v = (e0 * fc + e1 * sc + e2 * pr) * isum;
    adjw[b * 256 + t] = v;
    if (*flag) ((bf16*)out)[4096 + b * 256 + t] = f2b(v);
    else       ((float*)out)[4096 + b * 256 + t] = v;
}

// =============================== K5: GAT stack (MFMA) ========================
__device__ __forceinline__ void ln_frag(const float (*ht)[68],
                                        const float* __restrict__ g, const float* __restrict__ bp,
                                        int quad, int lo, short8& a0, short8& a1)
{
    float v[16];
    const float4* r0 = (const float4*)(&ht[lo][quad * 8]);
    const float4* r1 = (const float4*)(&ht[lo][32 + quad * 8]);
    float4 p0 = r0[0], p1 = r0[1], p2 = r1[0], p3 = r1[1];
    v[0] = p0.x; v[1] = p0.y; v[2] = p0.z; v[3] = p0.w;
    v[4] = p1.x; v[5] = p1.y; v[6] = p1.z; v[7] = p1.w;
    v[8] = p2.x; v[9] = p2.y; v[10] = p2.z; v[11] = p2.w;
    v[12] = p3.x; v[13] = p3.y; v[14] = p3.z; v[15] = p3.w;
    float s = 0.f;
#pragma unroll
    for (int i = 0; i < 16; i++) s += v[i];
    s += __shfl_xor(s, 16); s += __shfl_xor(s, 32);
    float mean = s * (1.0f / 64.0f);
    float q = 0.f;
#pragma unroll
    for (int i = 0; i < 16; i++) { float d = v[i] - mean; q += d * d; }
    q += __shfl_xor(q, 16); q += __shfl_xor(q, 32);
    float rstd = rsqrtf(q * (1.0f / 64.0f) + 1e-5f);
    float4 g0 = *(const float4*)(g + quad * 8);
    float4 g1 = *(const float4*)(g + quad * 8 + 4);
    float4 g2 = *(const float4*)(g + 32 + quad * 8);
    float4 g3 = *(const float4*)(g + 32 + quad * 8 + 4);
    float4 b0 = *(const float4*)(bp + quad * 8);
    float4 b1 = *(const float4*)(bp + quad * 8 + 4);
    float4 b2 = *(const float4*)(bp + 32 + quad * 8);
    float4 b3 = *(const float4*)(bp + 32 + quad * 8 + 4);
    float gg[16] = {g0.x, g0.y, g0.z, g0.w, g1.x, g1.y, g1.z, g1.w,
                    g2.x, g2.y, g2.z, g2.w, g3.x, g3.y, g3.z, g3.w};
    float bb[16] = {b0.x, b0.y, b0.z, b0.w, b1.x, b1.y, b1.z, b1.w,
                    b2.x, b2.y, b2.z, b2.w, b3.x, b3.y, b3.z, b3.w};
    union { unsigned u[4]; short8 s8; } c0, c1;
#pragma unroll
    for (int i = 0; i < 4; i++) {
        float oa = (v[2 * i] - mean) * rstd * gg[2 * i] + bb[2 * i];
        float ob = (v[2 * i + 1] - mean) * rstd * gg[2 * i + 1] + bb[2 * i + 1];
        c0.u[i] = pack2bf(oa, ob);
        float oc = (v[8 + 2 * i] - mean) * rstd * gg[8 + 2 * i] + bb[8 + 2 * i];
        float od = (v[9 + 2 * i] - mean) * rstd * gg[9 + 2 * i] + bb[9 + 2 * i];
        c1.u[i] = pack2bf(oc, od);
    }
    a0 = c0.s8;
    a1 = c1.s8;
}

__global__ __launch_bounds__(256) void k_gat(
    const float* __restrict__ hm, const float* __restrict__ adjw,
    const ushort_t* __restrict__ wpk,
    const float* __restrict__ qb_, const float* __restrict__ ob_,
    const float* __restrict__ f1b_, const float* __restrict__ f2b_,
    const float* __restrict__ n1g_, const float* __restrict__ n1b_,
    const float* __restrict__ n2g_, const float* __restrict__ n2b_,
    const float* __restrict__ gng, const float* __restrict__ gnb,
    ushort_t* __restrict__ hmb)
{
    __shared__ float htw_all[4][16][68];
    __shared__ ushort_t qkb_all[4][16][200];
    __shared__ ushort_t vt_all[4][64][16];
    int t = threadIdx.x;
    int w = t >> 6, l = t & 63;
    int quad = l >> 4, lo = l & 15;
    int n = blockIdx.x * 4 + w;
    int b = n >> 8, tp = n & 255;
    float (*htw)[68] = htw_all[w];
    ushort_t (*qkb)[200] = qkb_all[w];
    ushort_t (*vt)[16] = vt_all[w];
    const float* src = hm + (size_t)b * 16 * 16384 + (size_t)tp * 64;
#pragma unroll
    for (int c = 0; c < 16; c++) htw[c][l] = src[(size_t)c * 16384 + l];
    float adjr[4];
#pragma unroll
    for (int r = 0; r < 4; r++) adjr[r] = adjw[b * 256 + (quad * 4 + r) * 16 + lo];

    for (int layer = 0; layer < 2; layer++) {
        const ushort_t* wq  = wpk + layer * 12288;
        const ushort_t* wo  = wpk + 24576 + layer * 4096;
        const ushort_t* wf1 = wpk + 32768 + layer * 8192;
        const ushort_t* wf2 = wpk + 49152 + layer * 8192;
        const float* qb = qb_ + layer * 192;
        const float* ob = ob_ + layer * 64;
        const float* f1b = f1b_ + layer * 128;
        const float* f2b = f2b_ + layer * 64;

        short8 a0, a1;
        ln_frag(htw, n1g_ + layer * 64, n1b_ + layer * 64, quad, lo, a0, a1);

#pragma unroll
        for (int nt = 0; nt < 12; nt++) {
            const ushort_t* wr = wq + (nt * 16 + lo) * 64 + quad * 8;
            short8 b0 = *(const short8*)wr;
            short8 b1 = *(const short8*)(wr + 32);
            f32x4 acc = {0.f, 0.f, 0.f, 0.f};
            acc = __builtin_amdgcn_mfma_f32_16x16x32_bf16(a0, b0, acc, 0, 0, 0);
            acc = __builtin_amdgcn_mfma_f32_16x16x32_bf16(a1, b1, acc, 0, 0, 0);
            float bias = qb[nt * 16 + lo];
            if (nt < 8) {
#pragma unroll
                for (int r = 0; r < 4; r++) qkb[quad * 4 + r][nt * 16 + lo] = f2bu(acc[r] + bias);
            } else {
#pragma unroll
                for (int r = 0; r < 4; r++) vt[(nt - 8) * 16 + lo][quad * 4 + r] = f2bu(acc[r] + bias);
            }
        }

        short8 zf = {0, 0, 0, 0, 0, 0, 0, 0};
#pragma unroll
        for (int h = 0; h < 4; h++) {
            short8 qf = zf, kf = zf;
            if (quad < 2) {
                qf = *(const short8*)&qkb[lo][h * 16 + quad * 8];
                kf = *(const short8*)&qkb[lo][64 + h * 16 + quad * 8];
            }
            f32x4 s4 = {0.f, 0.f, 0.f, 0.f};
            s4 = __builtin_amdgcn_mfma_f32_16x16x32_bf16(qf, kf, s4, 0, 0, 0);
#pragma unroll
            for (int r = 0; r < 4; r++) {
                float sv = s4[r] * 0.25f + adjr[r];
                float mx = sv;
                mx = fmaxf(mx, __shfl_xor(mx, 1));
                mx = fmaxf(mx, __shfl_xor(mx, 2));
                mx = fmaxf(mx, __shfl_xor(mx, 4));
                mx = fmaxf(mx, __shfl_xor(mx, 8));
                float e = __expf(sv - mx);
                float sm = e;
                sm += __shfl_xor(sm, 1);
                sm += __shfl_xor(sm, 2);
                sm += __shfl_xor(sm, 4);
                sm += __shfl_xor(sm, 8);
                qkb[quad * 4 + r][h * 16 + lo] = f2bu(e / sm);
            }
        }
#pragma unroll
        for (int h = 0; h < 4; h++) {
            short8 pf = zf, vf = zf;
            if (quad < 2) {
                pf = *(const short8*)&qkb[lo][h * 16 + quad * 8];
                vf = *(const short8*)&vt[h * 16 + lo][quad * 8];
            }
            f32x4 oc = {0.f, 0.f, 0.f, 0.f};
            oc = __builtin_amdgcn_mfma_f32_16x16x32_bf16(pf, vf, oc, 0, 0, 0);
#pragma unroll
            for (int r = 0; r < 4; r++) qkb[quad * 4 + r][h * 16 + lo] = f2bu(oc[r]);
        }
        short8 pa0 = *(const short8*)&qkb[lo][quad * 8];
        short8 pa1 = *(const short8*)&qkb[lo][32 + quad * 8];
#pragma unroll
        for (int nt = 0; nt < 4; nt++) {
            const ushort_t* wr = wo + (nt * 16 + lo) * 64 + quad * 8;
            short8 b0 = *(const short8*)wr;
            short8 b1 = *(const short8*)(wr + 32);
            f32x4 acc = {0.f, 0.f, 0.f, 0.f};
            acc = __builtin_amdgcn_mfma_f32_16x16x32_bf16(pa0, b0, acc, 0, 0, 0);
            acc = __builtin_amdgcn_mfma_f32_16x16x32_bf16(pa1, b1, acc, 0, 0, 0);
            float bias = ob[nt * 16 + lo];
#pragma unroll
            for (int r = 0; r < 4; r++) htw[quad * 4 + r][nt * 16 + lo] += acc[r] + bias;
        }
        short8 fa0, fa1;
        ln_frag(htw, n2g_ + layer * 64, n2b_ + layer * 64, quad, lo, fa0, fa1);
#pragma unroll
        for (int nt = 0; nt < 8; nt++) {
            const ushort_t* wr = wf1 + (nt * 16 + lo) * 64 + quad * 8;
            short8 b0 = *(const short8*)wr;
            short8 b1 = *(const short8*)(wr + 32);
            f32x4 acc = {0.f, 0.f, 0.f, 0.f};
            acc = __builtin_amdgcn_mfma_f32_16x16x32_bf16(fa0, b0, acc, 0, 0, 0);
            acc = __builtin_amdgcn_mfma_f32_16x16x32_bf16(fa1, b1, acc, 0, 0, 0);
            float bias = f1b[nt * 16 + lo];
#pragma unroll
            for (int r = 0; r < 4; r++) qkb[quad * 4 + r][nt * 16 + lo] = f2bu(geluf(acc[r] + bias));
        }
        short8 ga[4];
#pragma unroll
        for (int kb = 0; kb < 4; kb++) ga[kb] = *(const short8*)&qkb[lo][kb * 32 + quad * 8];
#pragma unroll
        for (int nt = 0; nt < 4; nt++) {
            const ushort_t* wr = wf2 + (nt * 16 + lo) * 128 + quad * 8;
            f32x4 acc = {0.f, 0.f, 0.f, 0.f};
#pragma unroll
            for (int kb = 0; kb < 4; kb++) {
                short8 bb = *(const short8*)(wr + kb * 32);
                acc = __builtin_amdgcn_mfma_f32_16x16x32_bf16(ga[kb], bb, acc, 0, 0, 0);
            }
            float bias = f2b[nt * 16 + lo];
#pragma unroll
            for (int r = 0; r < 4; r++) htw[quad * 4 + r][nt * 16 + lo] += acc[r] + bias;
        }
    }
    // ---- final LN -> bf16 hmb (same per-lane column ownership) ----
    {
        float v[16];
        const float4* r0 = (const float4*)(&htw[lo][quad * 8]);
        const float4* r1 = (const float4*)(&htw[lo][32 + quad * 8]);
        float4 p0 = r0[0], p1 = r0[1], p2 = r1[0], p3 = r1[1];
        v[0] = p0.x; v[1] = p0.y; v[2] = p0.z; v[3] = p0.w;
        v[4] = p1.x; v[5] = p1.y; v[6] = p1.z; v[7] = p1.w;
        v[8] = p2.x; v[9] = p2.y; v[10] = p2.z; v[11] = p2.w;
        v[12] = p3.x; v[13] = p3.y; v[14] = p3.z; v[15] = p3.w;
        float s = 0.f;
#pragma unroll
        for (int i = 0; i < 16; i++) s += v[i];
        s += __shfl_xor(s, 16); s += __shfl_xor(s, 32);
        float mean = s * (1.0f / 64.0f);
        float q = 0.f;
#pragma unroll
        for (int i = 0; i < 16; i++) { float d = v[i] - mean; q += d * d; }
        q += __shfl_xor(q, 16); q += __shfl_xor(q, 32);
        float rstd = rsqrtf(q * (1.0f / 64.0f) + 1e-5f);
        float4 g0 = *(const float4*)(gng + quad * 8);
        float4 g1 = *(const float4*)(gng + quad * 8 + 4);
        float4 g2 = *(const float4*)(gng + 32 + quad * 8);
        float4 g3 = *(const float4*)(gng + 32 + quad * 8 + 4);
        float4 b0 = *(const float4*)(gnb + quad * 8);
        float4 b1 = *(const float4*)(gnb + quad * 8 + 4);
        float4 b2 = *(const float4*)(gnb + 32 + quad * 8);
        float4 b3 = *(const float4*)(gnb + 32 + quad * 8 + 4);
        float gg[16] = {g0.x, g0.y, g0.z, g0.w, g1.x, g1.y, g1.z, g1.w,
                        g2.x, g2.y, g2.z, g2.w, g3.x, g3.y, g3.z, g3.w};
        float bb[16] = {b0.x, b0.y, b0.z, b0.w, b1.x, b1.y, b1.z, b1.w,
                        b2.x, b2.y, b2.z, b2.w, b3.x, b3.y, b3.z, b3.w};
        unsigned u[8];
#pragma unroll
        for (int i = 0; i < 4; i++) {
            float oa = (v[2 * i] - mean) * rstd * gg[2 * i] + bb[2 * i];
            float obv = (v[2 * i + 1] - mean) * rstd * gg[2 * i + 1] + bb[2 * i + 1];
            u[i] = pack2bf(oa, obv);
            float oc = (v[8 + 2 * i] - mean) * rstd * gg[8 + 2 * i] + bb[8 + 2 * i];
            float od = (v[9 + 2 * i] - mean) * rstd * gg[9 + 2 * i] + bb[9 + 2 * i];
            u[4 + i] = pack2bf(oc, od);
        }
        ushort_t* dst = hmb + (size_t)(b * 16 + lo) * 16384 + (size_t)tp * 64;
        *(uint4*)(dst + quad * 8) = make_uint4(u[0], u[1], u[2], u[3]);
        *(uint4*)(dst + 32 + quad * 8) = make_uint4(u[4], u[5], u[6], u[7]);
    }
}

// =============================== K6: GRU (MFMA, W-as-A) ======================
__global__ __launch_bounds__(256) void k_gru(
    const ushort_t* __restrict__ hmb, const ushort_t* __restrict__ wgru,
    const float* __restrict__ bih_, const float* __restrict__ bhh_,
    float* __restrict__ h_out)
{
    __shared__ ushort_t hbuf[2][16][72];
    int t = threadIdx.x;
    int w = t >> 6, l = t & 63;
    int lo = l & 15, qd = l >> 4;
    int dir = blockIdx.x >> 5;
    int cseq0 = (blockIdx.x & 31) * 16;
    const ushort_t* wih = wgru + dir * 12288;
    const ushort_t* whh = wgru + 24576 + dir * 12288;
    const ushort_t* pr0 = wih + ((w) * 16 + lo) * 64 + qd * 8;
    const ushort_t* pz0 = wih + ((4 + w) * 16 + lo) * 64 + qd * 8;
    const ushort_t* pn0 = wih + ((8 + w) * 16 + lo) * 64 + qd * 8;
    const ushort_t* hr0 = whh + ((w) * 16 + lo) * 64 + qd * 8;
    const ushort_t* hz0 = whh + ((4 + w) * 16 + lo) * 64 + qd * 8;
    const ushort_t* hn0 = whh + ((8 + w) * 16 + lo) * 64 + qd * 8;
    short8 wi_r0 = *(const short8*)pr0, wi_r1 = *(const short8*)(pr0 + 32);
    short8 wi_z0 = *(const short8*)pz0, wi_z1 = *(const short8*)(pz0 + 32);
    short8 wi_n0 = *(const short8*)pn0, wi_n1 = *(const short8*)(pn0 + 32);
    short8 wh_r0 = *(const short8*)hr0, wh_r1 = *(const short8*)(hr0 + 32);
    short8 wh_z0 = *(const short8*)hz0, wh_z1 = *(const short8*)(hz0 + 32);
    short8 wh_n0 = *(const short8*)hn0, wh_n1 = *(const short8*)(hn0 + 32);
    int d_base = w * 16 + qd * 4;
    float bsr[4], bsz[4], bin[4], bhn[4];
#pragma unroll
    for (int r = 0; r < 4; r++) {
        bsr[r] = bih_[dir * 192 + d_base + r] + bhh_[dir * 192 + d_base + r];
        bsz[r] = bih_[dir * 192 + 64 + d_base + r] + bhh_[dir * 192 + 64 + d_base + r];
        bin[r] = bih_[dir * 192 + 128 + d_base + r];
        bhn[r] = bhh_[dir * 192 + 128 + d_base + r];
    }
    const ushort_t* xrow = hmb + (size_t)(cseq0 + lo) * 16384 + qd * 8;
    for (int i = t; i < 2 * 16 * 72; i += 256) ((ushort_t*)hbuf)[i] = 0;
    float h_old[4] = {0.f, 0.f, 0.f, 0.f};

    int s0 = dir ? 255 : 0;
    int s1 = dir ? 254 : 1;
    int s2 = dir ? 253 : 2;
    short8 xc0 = *(const short8*)(xrow + s0 * 64);
    short8 xc1 = *(const short8*)(xrow + s0 * 64 + 32);
    short8 xA0 = *(const short8*)(xrow + s1 * 64);
    short8 xA1 = *(const short8*)(xrow + s1 * 64 + 32);
    short8 xB0 = *(const short8*)(xrow + s2 * 64);
    short8 xB1 = *(const short8*)(xrow + s2 * 64 + 32);
    f32x4 axr = {0.f, 0.f, 0.f, 0.f}, axz = {0.f, 0.f, 0.f, 0.f}, axn = {0.f, 0.f, 0.f, 0.f};
    axr = __builtin_amdgcn_mfma_f32_16x16x32_bf16(wi_r0, xc0, axr, 0, 0, 0);
    axr = __builtin_amdgcn_mfma_f32_16x16x32_bf16(wi_r1, xc1, axr, 0, 0, 0);
    axz = __builtin_amdgcn_mfma_f32_16x16x32_bf16(wi_z0, xc0, axz, 0, 0, 0);
    axz = __builtin_amdgcn_mfma_f32_16x16x32_bf16(wi_z1, xc1, axz, 0, 0, 0);
    axn = __builtin_amdgcn_mfma_f32_16x16x32_bf16(wi_n0, xc0, axn, 0, 0, 0);
    axn = __builtin_amdgcn_mfma_f32_16x16x32_bf16(wi_n1, xc1, axn, 0, 0, 0);
    __syncthreads();
#pragma unroll 2
    for (int step = 0; step < 256; step++) {
        int cur = step & 1, nxt = cur ^ 1;
        f32x4 nxr = {0.f, 0.f, 0.f, 0.f}, nxz = {0.f, 0.f, 0.f, 0.f}, nxn = {0.f, 0.f, 0.f, 0.f};
        nxr = __builtin_amdgcn_mfma_f32_16x16x32_bf16(wi_r0, xA0, nxr, 0, 0, 0);
        nxr = __builtin_amdgcn_mfma_f32_16x16x32_bf16(wi_r1, xA1, nxr, 0, 0, 0);
        nxz = __builtin_amdgcn_mfma_f32_16x16x32_bf16(wi_z0, xA0, nxz, 0, 0, 0);
        nxz = __builtin_amdgcn_mfma_f32_16x16x32_bf16(wi_z1, xA1, nxz, 0, 0, 0);
        nxn = __builtin_amdgcn_mfma_f32_16x16x32_bf16(wi_n0, xA0, nxn, 0, 0, 0);
        nxn = __builtin_amdgcn_mfma_f32_16x16x32_bf16(wi_n1, xA1, nxn, 0, 0, 0);
        xA0 = xB0; xA1 = xB1;
        int tl = step + 3 > 255 ? 255 : step + 3;
        int sf = dir ? 255 - tl : tl;
        xB0 = *(const short8*)(xrow + sf * 64);
        xB1 = *(const short8*)(xrow + sf * 64 + 32);
        short8 bh0 = *(const short8*)&hbuf[cur][lo][qd * 8];
        short8 bh1 = *(const short8*)&hbuf[cur][lo][32 + qd * 8];
        f32x4 ar = axr, az = axz;
        f32x4 anh = {0.f, 0.f, 0.f, 0.f};
        ar = __builtin_amdgcn_mfma_f32_16x16x32_bf16(wh_r0, bh0, ar, 0, 0, 0);
        ar = __builtin_amdgcn_mfma_f32_16x16x32_bf16(wh_r1, bh1, ar, 0, 0, 0);
        az = __builtin_amdgcn_mfma_f32_16x16x32_bf16(wh_z0, bh0, az, 0, 0, 0);
        az = __builtin_amdgcn_mfma_f32_16x16x32_bf16(wh_z1, bh1, az, 0, 0, 0);
        anh = __builtin_amdgcn_mfma_f32_16x16x32_bf16(wh_n0, bh0, anh, 0, 0, 0);
        anh = __builtin_amdgcn_mfma_f32_16x16x32_bf16(wh_n1, bh1, anh, 0, 0, 0);
        float hv[4];
#pragma unroll
        for (int r = 0; r < 4; r++) {
            float gr = sigmoidf_(ar[r] + bsr[r]);
            float gz = sigmoidf_(az[r] + bsz[r]);
            float nin = (axn[r] + bin[r]) + gr * (anh[r] + bhn[r]);
            nin = fminf(fmaxf(nin, -15.f), 15.f);
            float e = __expf(-2.f * nin);
            float gn = (1.f - e) / (1.f + e);
            float hn = gn + gz * (h_old[r] - gn);
            h_old[r] = hn;
            hv[r] = hn;
        }
        *(uint2*)&hbuf[nxt][lo][d_base] = make_uint2(pack2bf(hv[0], hv[1]), pack2bf(hv[2], hv[3]));
        asm volatile("s_waitcnt lgkmcnt(0)\n\ts_barrier" ::: "memory");
        axr = nxr; axz = nxz; axn = nxn;
    }
    *(float4*)&h_out[(size_t)(cseq0 + lo) * 128 + dir * 64 + d_base] =
        make_float4(h_old[0], h_old[1], h_old[2], h_old[3]);
}

// =============================== K7: readout =================================
__global__ __launch_bounds__(128) void k_readout(
    const float* __restrict__ h_out, const float* __restrict__ gw, const float* __restrict__ gb,
    void* __restrict__ out, const int* __restrict__ flag)
{
    __shared__ float gate_s[16];
    __shared__ float gws[128];
    int b = blockIdx.x, t = threadIdx.x;
    gws[t] = gw[t];
    __syncthreads();
    int isb = *flag;
    if (t < 16) {
        const float* hr = h_out + (size_t)(b * 16 + t) * 128;
        float acc = gb[0];
        for (int k = 0; k < 128; k++) acc += hr[k] * gws[k];
        float g = sigmoidf_(acc);
        gate_s[t] = g;
        if (isb) ((bf16*)out)[12288 + b * 16 + t] = f2b(g);
        else     ((float*)out)[12288 + b * 16 + t] = g;
    }
    __syncthreads();
    float den = 1e-8f;
#pragma unroll
    for (int c = 0; c < 16; c++) den += gate_s[c];
    float num = 0.f;
#pragma unroll
    for (int c = 0; c < 16; c++) num += h_out[(size_t)(b * 16 + c) * 128 + t] * gate_s[c];
    float v = num / den;
    if (isb) ((bf16*)out)[b * 128 + t] = f2b(v);
    else     ((float*)out)[b * 128 + t] = v;
}

// =============================== launch ======================================
extern "C" void kernel_launch(void* const* d_in, const int* in_sizes, int n_in,
                              void* d_out, int out_size, void* d_ws, size_t ws_size,
                              hipStream_t stream)
{
    int* flag = (int*)d_ws;
    float* cvt = (float*)((char*)d_ws + 256);

    InPtrs P;
    InOffs O;
    int cum = 0;
    for (int i = 0; i < 35; i++) {
        P.p[i] = d_in[i];
        O.off[i] = cum;
        O.sz[i] = in_sizes[i];
        cum += (in_sizes[i] + 7) & ~7;
    }
    int total = cum;

    const float* x     = cvt + O.off[0];
    const float* c1w   = cvt + O.off[1];
    const float* c1b   = cvt + O.off[2];
    const float* bn1g  = cvt + O.off[3];
    const float* bn1b  = cvt + O.off[4];
    const float* bn1m  = cvt + O.off[5];
    const float* bn1v  = cvt + O.off[6];
    const float* c2w   = cvt + O.off[7];
    const float* c2b   = cvt + O.off[8];
    const float* bn2g  = cvt + O.off[9];
    const float* bn2b  = cvt + O.off[10];
    const float* bn2m  = cvt + O.off[11];
    const float* bn2v  = cvt + O.off[12];
    const float* prior = cvt + O.off[13];
    const float* logw  = cvt + O.off[14];
    const float* n1g   = cvt + O.off[15];
    const float* n1b   = cvt + O.off[16];
    const float* qkvw  = cvt + O.off[17];
    const float* qkvb  = cvt + O.off[18];
    const float* outw  = cvt + O.off[19];
    const float* outb  = cvt + O.off[20];
    const float* n2g   = cvt + O.off[21];
    const float* n2b   = cvt + O.off[22];
    const float* f1w   = cvt + O.off[23];
    const float* f1b   = cvt + O.off[24];
    const float* f2w   = cvt + O.off[25];
    const float* f2b_  = cvt + O.off[26];
    const float* gng   = cvt + O.off[27];
    const float* gnb   = cvt + O.off[28];
    const float* gwih  = cvt + O.off[29];
    const float* gwhh  = cvt + O.off[30];
    const float* gbih  = cvt + O.off[31];
    const float* gbhh  = cvt + O.off[32];
    const float* gatew = cvt + O.off[33];
    const float* gateb = cvt + O.off[34];

    float* fbase = cvt + ((total + 63) & ~63);
    float* hm    = fbase;                              // 8388608 floats (CNN out)
    ushort_t* Xnb = (ushort_t*)(hm + 8388608);         // 512*2080 bf16 spectrum
    float* hnf   = fbase + 8921088;                    // 32768
    float* adjw  = hnf + 32768;                        // 8192
    float* hout  = adjw + 8192;                        // 65536
    unsigned* wpk = (unsigned*)(hout + 65536);         // 62464 uints (bf16 weights)
    ushort_t* hmb = (ushort_t*)(wpk + 62464);          // 8388608 bf16 (GAT out)

    k_detect<<<1, 256, 0, stream>>>((const unsigned*)d_in[0], flag);
    k_convert<<<(total + 255) / 256, 256, 0, stream>>>(P, O, total, flag, cvt);
    k_pack<<<244, 256, 0, stream>>>(qkvw, outw, f1w, f2w, gwih, gwhh, c2w, wpk);
    k_front<<<768, 256, 0, stream>>>(x, c1w, c1b, bn1g, bn1b, bn1m, bn1v,
                                     c2b, bn2g, bn2b, bn2m, bn2v,
                                     (const ushort_t*)(wpk + 57344), hm, Xnb, hnf);
    k_adj<<<32, 256, 0, stream>>>(Xnb, hnf, prior, logw, adjw, d_out, flag);
    k_gat<<<2048, 256, 0, stream>>>(hm, adjw, (const ushort_t*)wpk,
                                    qkvb, outb, f1b, f2b_, n1g, n1b, n2g, n2b, gng, gnb, hmb);
    k_gru<<<64, 256, 0, stream>>>(hmb, (const ushort_t*)(wpk + 32768), gbih, gbhh, hout);
    k_readout<<<32, 128, 0, stream>>>(hout, gatew, gateb, d_out, flag);
}

// Round 12
// 546.246 us; speedup vs baseline: 1.1058x; 1.0279x over previous
//
#include <hip/hip_runtime.h>
#include <hip/hip_bf16.h>
#include <math.h>

typedef __hip_bfloat16 bf16;
typedef unsigned short ushort_t;
typedef __attribute__((ext_vector_type(8))) short short8;
typedef __attribute__((ext_vector_type(4))) float f32x4;

__device__ __forceinline__ float b2f(bf16 v) { return __bfloat162float(v); }
__device__ __forceinline__ bf16 f2b(float v) { return __float2bfloat16(v); }
__device__ __forceinline__ float sigmoidf_(float x) { return 1.0f / (1.0f + __expf(-x)); }

// DPP cross-lane on the VALU pipe (keeps the LDS pipe free).
// quad_perm 0xB1 = lane^1, 0x4E = lane^2; row_ror 0x120|k rotates within 16.
template<int CTRL>
__device__ __forceinline__ float dpp_mov(float v) {
    return __int_as_float(__builtin_amdgcn_update_dpp(0, __float_as_int(v), CTRL, 0xF, 0xF, false));
}
__device__ __forceinline__ float dpp_row_sum16(float v) {
    v += dpp_mov<0x128>(v);
    v += dpp_mov<0x124>(v);
    v += dpp_mov<0x122>(v);
    v += dpp_mov<0x121>(v);
    return v;
}

// fast exact-gelu: erf via Abramowitz-Stegun 7.1.26 (|err| <= 1.5e-7)
__device__ __forceinline__ float geluf(float x) {
    float z = x * 0.70710678118654752f;
    float az = fabsf(z);
    float t = 1.0f / (1.0f + 0.3275911f * az);
    float poly = ((((1.061405429f * t - 1.453152027f) * t + 1.421413741f) * t
                   - 0.284496736f) * t + 0.254829592f) * t;
    float erfa = 1.0f - poly * __expf(-z * z);
    float er = (z < 0.f) ? -erfa : erfa;
    return 0.5f * x * (1.0f + er);
}

__device__ __forceinline__ unsigned pack2bf(float a, float b) {
    unsigned ua = __float_as_uint(a); ua = (ua + 0x7FFFu + ((ua >> 16) & 1u)) >> 16;
    unsigned ub = __float_as_uint(b); ub = (ub + 0x7FFFu + ((ub >> 16) & 1u)) >> 16;
    return ua | (ub << 16);
}
__device__ __forceinline__ ushort_t f2bu(float v) {
    unsigned u = __float_as_uint(v);
    u = (u + 0x7FFFu + ((u >> 16) & 1u)) >> 16;
    return (ushort_t)u;
}

// ========================== K0a: dtype detector ==============================
__global__ __launch_bounds__(256) void k_detect(const unsigned* __restrict__ x, int* __restrict__ flag)
{
    __shared__ int cnt;
    if (threadIdx.x == 0) cnt = 0;
    __syncthreads();
    unsigned u = x[threadIdx.x] & 0xFFFFu;
    float f = __uint_as_float(u << 16);
    float a = fabsf(f);
    int sane = (f == 0.0f) || (a > 1e-8f && a < 1e4f);
    atomicAdd(&cnt, sane);
    __syncthreads();
    if (threadIdx.x == 0) *flag = (cnt >= 160) ? 1 : 0;
}

// ========================== K0b: canonicalize to fp32 ========================
struct InPtrs { const void* p[35]; };
struct InOffs { int off[35]; int sz[35]; };

__global__ __launch_bounds__(256) void k_convert(InPtrs P, InOffs O, int total,
                                                 const int* __restrict__ flag,
                                                 float* __restrict__ cvt)
{
    int idx = blockIdx.x * 256 + threadIdx.x;
    if (idx >= total) return;
    int isb = *flag;
    float v = 0.f;
    if (idx < O.sz[0]) {
        v = isb ? b2f(((const bf16*)P.p[0])[idx]) : ((const float*)P.p[0])[idx];
    } else {
#pragma unroll 1
        for (int s = 1; s < 35; s++) {
            int rel = idx - O.off[s];
            if (rel >= 0 && rel < O.sz[s]) {
                v = isb ? b2f(((const bf16*)P.p[s])[rel]) : ((const float*)P.p[s])[rel];
                break;
            }
        }
    }
    cvt[idx] = v;
}

// ========================== K0c: pack weights to bf16 ========================
__global__ __launch_bounds__(256) void k_pack(const float* __restrict__ qw, const float* __restrict__ ow,
                                              const float* __restrict__ f1w, const float* __restrict__ f2w,
                                              const float* __restrict__ gwih, const float* __restrict__ gwhh,
                                              const float* __restrict__ c2w,
                                              unsigned* __restrict__ dst)
{
    int i = blockIdx.x * 256 + threadIdx.x;
    if (i >= 62464) return;
    if (i >= 57344) {
        int j0 = (i - 57344) * 2;
        int tap = j0 >> 11, rem = j0 & 2047;
        int d = rem >> 5, ic = rem & 31;
        dst[i] = pack2bf(c2w[d * 160 + ic * 5 + tap], c2w[d * 160 + (ic + 1) * 5 + tap]);
        return;
    }
    const float* s; int rel;
    if (i < 12288)      { s = qw;   rel = i; }
    else if (i < 16384) { s = ow;   rel = i - 12288; }
    else if (i < 24576) { s = f1w;  rel = i - 16384; }
    else if (i < 32768) { s = f2w;  rel = i - 24576; }
    else if (i < 45056) { s = gwih; rel = i - 32768; }
    else                { s = gwhh; rel = i - 45056; }
    dst[i] = pack2bf(s[2 * rel], s[2 * rel + 1]);
}

// ====================== K1: fused front (CNN+havg | pair-FFT) ================
__global__ __launch_bounds__(256) void k_front(
    const float* __restrict__ x,
    const float* __restrict__ c1w, const float* __restrict__ c1b,
    const float* __restrict__ bn1g, const float* __restrict__ bn1b, const float* __restrict__ bn1m, const float* __restrict__ bn1v,
    const float* __restrict__ c2b,
    const float* __restrict__ bn2g, const float* __restrict__ bn2b, const float* __restrict__ bn2m, const float* __restrict__ bn2v,
    const ushort_t* __restrict__ w2pk,
    float* __restrict__ h_main, ushort_t* __restrict__ Xnb, float* __restrict__ hnf)
{
    __shared__ float smem[9984];
    int t = threadIdx.x;
    if (blockIdx.x >= 512) {
        // ---------------- pair-FFT path ----------------
        float* re = smem;
        float* im = smem + 4096;
        float* red = smem + 8192;
        int bc2 = blockIdx.x - 512;            // 0..255
        int b = bc2 >> 3, cp = bc2 & 7;
        const float* xa = x + ((size_t)b * 16 + 2 * cp) * 4096;
        const float* xb = xa + 4096;
        for (int i = t; i < 4096; i += 256) {
            int r = __brev((unsigned)i) >> 20;
            re[r] = xa[i];
            im[r] = xb[i];
        }
        __syncthreads();
        for (int s = 1; s <= 12; s++) {
            int half = 1 << (s - 1);
            float ang = -6.283185307179586f / (float)(1 << s);
            for (int m = t; m < 2048; m += 256) {
                int j = m & (half - 1);
                int pos = ((m >> (s - 1)) << s) | j;
                float sn, cs;
                __sincosf(ang * (float)j, &sn, &cs);
                float ur = re[pos], ui = im[pos];
                float vr = re[pos + half], vi = im[pos + half];
                float tr = vr * cs - vi * sn;
                float ti = vr * sn + vi * cs;
                re[pos] = ur + tr; im[pos] = ui + ti;
                re[pos + half] = ur - tr; im[pos + half] = ui - ti;
            }
            __syncthreads();
        }
        float maga[9], magb[9];
        float ssa = 0.f, ssb = 0.f;
#pragma unroll
        for (int it = 0; it < 9; it++) {
            int k = t + it * 256;
            float ma = 0.f, mb = 0.f;
            if (k <= 2048) {
                int kn = (4096 - k) & 4095;
                float Rk = re[k], Ik = im[k], Rn = re[kn], In = im[kn];
                float ra = 0.5f * (Rk + Rn), ia = 0.5f * (Ik - In);
                float rb = 0.5f * (Ik + In), ib = 0.5f * (Rn - Rk);
                ma = sqrtf(ra * ra + ia * ia);
                mb = sqrtf(rb * rb + ib * ib);
                ssa += ma * ma; ssb += mb * mb;
            }
            maga[it] = ma; magb[it] = mb;
        }
        for (int off = 32; off; off >>= 1) { ssa += __shfl_xor(ssa, off, 64); ssb += __shfl_xor(ssb, off, 64); }
        int w = t >> 6;
        if ((t & 63) == 0) { red[w] = ssa; red[4 + w] = ssb; }
        __syncthreads();
        float inva = 1.0f / (sqrtf(red[0] + red[1] + red[2] + red[3]) + 1e-8f);
        float invb = 1.0f / (sqrtf(red[4] + red[5] + red[6] + red[7]) + 1e-8f);
        ushort_t* rowa = Xnb + ((size_t)b * 16 + 2 * cp) * 2080;
        ushort_t* rowb = rowa + 2080;
#pragma unroll
        for (int it = 0; it < 9; it++) {
            int k = t + it * 256;
            if (k <= 2048) {
                rowa[k] = f2bu(maga[it] * inva);
                rowb[k] = f2bu(magb[it] * invb);
            }
        }
        for (int f = 2049 + t; f < 2080; f += 256) { rowa[f] = 0; rowb[f] = 0; }
        return;
    }
    // ---------------- CNN path ----------------
    float* ubuf = smem;                           // 4352 floats
    ushort_t* h1t = (ushort_t*)(smem + 4352);     // 10400 ushorts (260 rows x 40)
    float* A2s = smem + 9552;
    float* B2s = smem + 9616;
    float* hsum = smem + 9680;                    // 256
    int bc = blockIdx.x;
    int l = t & 63, w = t >> 6;
    int lo = l & 15, quad = l >> 4;

    if (t < 64) {
        float s = bn2g[t] * rsqrtf(bn2v[t] + 1e-5f);
        A2s[t] = s; B2s[t] = (c2b[t] - bn2m[t]) * s + bn2b[t];
    }
    int icp = t & 15;
    float w1r[2][7], A1r[2], B1r[2];
#pragma unroll
    for (int s = 0; s < 2; s++) {
        int ic = icp * 2 + s;
#pragma unroll
        for (int k = 0; k < 7; k++) w1r[s][k] = c1w[ic * 7 + k];
        float sc = bn1g[ic] * rsqrtf(bn1v[ic] + 1e-5f);
        A1r[s] = sc; B1r[s] = (c1b[ic] - bn1m[ic]) * sc + bn1b[ic];
    }
    short8 Afr[4][5];
#pragma unroll
    for (int dt = 0; dt < 4; dt++)
#pragma unroll
        for (int tap = 0; tap < 5; tap++)
            Afr[dt][tap] = *(const short8*)(w2pk + ((tap * 64 + dt * 16 + lo) * 32 + quad * 8));

    const float* xrow = x + (size_t)bc * 4096;
    float rs = 0.f;
    int dd = t & 63, pg = t >> 6;
    int rsel = lo & 3;
    for (int tile = 0; tile < 4; tile++) {
        int X0 = 1024 * tile - 11;
        for (int i = t; i < 1056; i += 256) {
            int g = X0 + i;
            ubuf[i] = (g >= 0 && g < 4096) ? xrow[g] : 0.0f;
        }
        __syncthreads();
        for (int pos = (t >> 4); pos < 260; pos += 16) {
            const float4* xw = (const float4*)&ubuf[4 * pos];
            float4 fa = xw[0], fb = xw[1], fc = xw[2];
            float xv[12] = {fa.x, fa.y, fa.z, fa.w, fb.x, fb.y, fb.z, fb.w,
                            fc.x, fc.y, fc.z, fc.w};
            int t1pg = tile * 256 + pos - 2;
            bool ok = (t1pg >= 0 && t1pg < 1024);
            float res[2];
#pragma unroll
            for (int s = 0; s < 2; s++) {
                float a0 = 0.f, a1 = 0.f, a2 = 0.f, a3 = 0.f;
#pragma unroll
                for (int k = 0; k < 7; k++) {
                    float wv = w1r[s][k];
                    a0 += xv[k] * wv;     a1 += xv[k + 1] * wv;
                    a2 += xv[k + 2] * wv; a3 += xv[k + 3] * wv;
                }
                float A = A1r[s], B = B1r[s];
                a0 = a0 * A + B; a1 = a1 * A + B; a2 = a2 * A + B; a3 = a3 * A + B;
                float mx = fmaxf(fmaxf(a0, a1), fmaxf(a2, a3));
                float mn = fminf(fminf(a0, a1), fminf(a2, a3));
                res[s] = ok ? fmaxf(geluf(mx), geluf(mn)) : 0.0f;
            }
            ((unsigned*)h1t)[pos * 20 + icp] = pack2bf(res[0], res[1]);
        }
        __syncthreads();
        float* houtile = ubuf;
#pragma unroll
        for (int ni = 0; ni < 4; ni++) {
            int nt = w * 4 + ni;
            short8 bfr[5];
#pragma unroll
            for (int tap = 0; tap < 5; tap++)
                bfr[tap] = *(const short8*)&h1t[(nt * 16 + lo + tap) * 40 + quad * 8];
#pragma unroll
            for (int dt = 0; dt < 4; dt++) {
                f32x4 acc = {0.f, 0.f, 0.f, 0.f};
#pragma unroll
                for (int tap = 0; tap < 5; tap++)
                    acc = __builtin_amdgcn_mfma_f32_16x16x32_bf16(Afr[dt][tap], bfr[tap], acc, 0, 0, 0);
                const float4 a2 = *(const float4*)&A2s[dt * 16 + quad * 4];
                const float4 b2 = *(const float4*)&B2s[dt * 16 + quad * 4];
                float a2a[4] = {a2.x, a2.y, a2.z, a2.w};
                float b2a[4] = {b2.x, b2.y, b2.z, b2.w};
                // DPP quad_perm butterfly (VALU pipe, not LDS); lane rsel owns r==rsel
                float mnr = 0.f, mxr = 0.f;
#pragma unroll
                for (int r = 0; r < 4; r++) {
                    float v = acc[r] * a2a[r] + b2a[r];
                    float o1 = dpp_mov<0xB1>(v);
                    float mx = fmaxf(v, o1), mn = fminf(v, o1);
                    mx = fmaxf(mx, dpp_mov<0x4E>(mx));
                    mn = fminf(mn, dpp_mov<0x4E>(mn));
                    if (rsel == r) { mnr = mn; mxr = mx; }
                }
                float res = fmaxf(geluf(mxr), geluf(mnr));
                houtile[(nt * 4 + (lo >> 2)) * 68 + dt * 16 + quad * 4 + rsel] = res;
            }
        }
        __syncthreads();
#pragma unroll
        for (int i = 0; i < 16; i++) rs += ubuf[(pg * 16 + i) * 68 + dd];
        float* dst = h_main + (size_t)bc * 16384 + tile * 4096;
        for (int i = t * 4; i < 4096; i += 1024) {
            float4 v = *(const float4*)&ubuf[(i >> 6) * 68 + (i & 63)];
            *(float4*)&dst[i] = v;
        }
        __syncthreads();
    }
    hsum[t] = rs;
    __syncthreads();
    if (t < 64) {
        float avg = (hsum[t] + hsum[64 + t] + hsum[128 + t] + hsum[192 + t]) * (1.0f / 256.0f);
        float tot = avg;
        for (int off = 32; off; off >>= 1) tot += __shfl_xor(tot, off, 64);
        float hc = avg - tot * (1.0f / 64.0f);
        float sq = hc * hc;
        for (int off = 32; off; off >>= 1) sq += __shfl_xor(sq, off, 64);
        hnf[bc * 64 + t] = hc / (sqrtf(sq) + 1e-8f);
    }
}

// =============================== K4: adjacency (MFMA) ========================
__global__ __launch_bounds__(256) void k_adj(
    const ushort_t* __restrict__ Xnb, const float* __restrict__ hnf,
    const float* __restrict__ prior, const float* __restrict__ logw,
    float* __restrict__ adjw, void* __restrict__ out, const int* __restrict__ flag)
{
    __shared__ float tile[4][16][17];
    __shared__ float hh[1024];
    int b = blockIdx.x, t = threadIdx.x;
    int w = t >> 6, l = t & 63;
    int lo = l & 15, quad = l >> 4;
    for (int i = t; i < 1024; i += 256) hh[i] = hnf[b * 1024 + i];
    const ushort_t* base = Xnb + (size_t)b * 16 * 2080 + lo * 2080 + quad * 8;
    f32x4 acc = {0.f, 0.f, 0.f, 0.f};
    for (int kb = w; kb < 65; kb += 4) {
        short8 f = *(const short8*)(base + kb * 32);
        acc = __builtin_amdgcn_mfma_f32_16x16x32_bf16(f, f, acc, 0, 0, 0);
    }
#pragma unroll
    for (int r = 0; r < 4; r++) tile[w][quad * 4 + r][lo] = acc[r];
    __syncthreads();
    int c = t >> 4, e = t & 15;
    float sc = tile[0][c][e] + tile[1][c][e] + tile[2][c][e] + tile[3][c][e];
    float fc = 0.f;
#pragma unroll
    for (int d = 0; d < 64; d++) fc += hh[c * 64 + d] * hh[e * 64 + d];
    float l0 = logw[0], l1 = logw[1], l2 = logw[2];
    float mx = fmaxf(l0, fmaxf(l1, l2));
    float e0 = __expf(l0 - mx), e1 = __expf(l1 - mx), e2 = __expf(l2 - mx);
    float isum = 1.0f / (e0 + e1 + e2);
    float pr = prior[c * 16 + e] + prior[e * 16 + c];
    float v = (e0 * fc + e1 * sc + e2 * pr) * isum;
    adjw[b * 256 + t] = v;
    if (*flag) ((bf16*)out)[4096 + b * 256 + t] = f2b(v);
    else       ((float*)out)[4096 + b * 256 + t] = v;
}

// =============================== K5: GAT stack (MFMA) ========================
__device__ __forceinline__ void ln_frag(const float (*ht)[68],
                                        const float* __restrict__ g, const float* __restrict__ bp,
                                        int quad, int lo, short8& a0, short8& a1)
{
    float v[16];
    const float4* r0 = (const float4*)(&ht[lo][quad * 8]);
    const float4* r1 = (const float4*)(&ht[lo][32 + quad * 8]);
    float4 p0 = r0[0], p1 = r0[1], p2 = r1[0], p3 = r1[1];
    v[0] = p0.x; v[1] = p0.y; v[2] = p0.z; v[3] = p0.w;
    v[4] = p1.x; v[5] = p1.y; v[6] = p1.z; v[7] = p1.w;
    v[8] = p2.x; v[9] = p2.y; v[10] = p2.z; v[11] = p2.w;
    v[12] = p3.x; v[13] = p3.y; v[14] = p3.z; v[15] = p3.w;
    float s = 0.f;
#pragma unroll
    for (int i = 0; i < 16; i++) s += v[i];
    s += __shfl_xor(s, 16); s += __shfl_xor(s, 32);
    float mean = s * (1.0f / 64.0f);
    float q = 0.f;
#pragma unroll
    for (int i = 0; i < 16; i++) { float d = v[i] - mean; q += d * d; }
    q += __shfl_xor(q, 16); q += __shfl_xor(q, 32);
    float rstd = rsqrtf(q * (1.0f / 64.0f) + 1e-5f);
    float4 g0 = *(const float4*)(g + quad * 8);
    float4 g1 = *(const float4*)(g + quad * 8 + 4);
    float4 g2 = *(const float4*)(g + 32 + quad * 8);
    float4 g3 = *(const float4*)(g + 32 + quad * 8 + 4);
    float4 b0 = *(const float4*)(bp + quad * 8);
    float4 b1 = *(const float4*)(bp + quad * 8 + 4);
    float4 b2 = *(const float4*)(bp + 32 + quad * 8);
    float4 b3 = *(const float4*)(bp + 32 + quad * 8 + 4);
    float gg[16] = {g0.x, g0.y, g0.z, g0.w, g1.x, g1.y, g1.z, g1.w,
                    g2.x, g2.y, g2.z, g2.w, g3.x, g3.y, g3.z, g3.w};
    float bb[16] = {b0.x, b0.y, b0.z, b0.w, b1.x, b1.y, b1.z, b1.w,
                    b2.x, b2.y, b2.z, b2.w, b3.x, b3.y, b3.z, b3.w};
    union { unsigned u[4]; short8 s8; } c0, c1;
#pragma unroll
    for (int i = 0; i < 4; i++) {
        float oa = (v[2 * i] - mean) * rstd * gg[2 * i] + bb[2 * i];
        float ob = (v[2 * i + 1] - mean) * rstd * gg[2 * i + 1] + bb[2 * i + 1];
        c0.u[i] = pack2bf(oa, ob);
        float oc = (v[8 + 2 * i] - mean) * rstd * gg[8 + 2 * i] + bb[8 + 2 * i];
        float od = (v[9 + 2 * i] - mean) * rstd * gg[9 + 2 * i] + bb[9 + 2 * i];
        c1.u[i] = pack2bf(oc, od);
    }
    a0 = c0.s8;
    a1 = c1.s8;
}

__global__ __launch_bounds__(256) void k_gat(
    const float* __restrict__ hm, const float* __restrict__ adjw,
    const ushort_t* __restrict__ wpk,
    const float* __restrict__ qb_, const float* __restrict__ ob_,
    const float* __restrict__ f1b_, const float* __restrict__ f2b_,
    const float* __restrict__ n1g_, const float* __restrict__ n1b_,
    const float* __restrict__ n2g_, const float* __restrict__ n2b_,
    const float* __restrict__ gng, const float* __restrict__ gnb,
    ushort_t* __restrict__ hmb)
{
    __shared__ float htw_all[4][16][68];
    __shared__ ushort_t qkb_all[4][16][200];
    __shared__ ushort_t vt_all[4][64][16];
    int t = threadIdx.x;
    int w = t >> 6, l = t & 63;
    int quad = l >> 4, lo = l & 15;
    int n = blockIdx.x * 4 + w;
    int b = n >> 8, tp = n & 255;
    float (*htw)[68] = htw_all[w];
    ushort_t (*qkb)[200] = qkb_all[w];
    ushort_t (*vt)[16] = vt_all[w];
    const float* src = hm + (size_t)b * 16 * 16384 + (size_t)tp * 64;
#pragma unroll
    for (int c = 0; c < 16; c++) htw[c][l] = src[(size_t)c * 16384 + l];
    float adjr[4];
#pragma unroll
    for (int r = 0; r < 4; r++) adjr[r] = adjw[b * 256 + (quad * 4 + r) * 16 + lo];

    for (int layer = 0; layer < 2; layer++) {
        const ushort_t* wq  = wpk + layer * 12288;
        const ushort_t* wo  = wpk + 24576 + layer * 4096;
        const ushort_t* wf1 = wpk + 32768 + layer * 8192;
        const ushort_t* wf2 = wpk + 49152 + layer * 8192;
        const float* qb = qb_ + layer * 192;
        const float* ob = ob_ + layer * 64;
        const float* f1b = f1b_ + layer * 128;
        const float* f2b = f2b_ + layer * 64;

        short8 a0, a1;
        ln_frag(htw, n1g_ + layer * 64, n1b_ + layer * 64, quad, lo, a0, a1);

#pragma unroll
        for (int nt = 0; nt < 12; nt++) {
            const ushort_t* wr = wq + (nt * 16 + lo) * 64 + quad * 8;
            short8 b0 = *(const short8*)wr;
            short8 b1 = *(const short8*)(wr + 32);
            f32x4 acc = {0.f, 0.f, 0.f, 0.f};
            acc = __builtin_amdgcn_mfma_f32_16x16x32_bf16(a0, b0, acc, 0, 0, 0);
            acc = __builtin_amdgcn_mfma_f32_16x16x32_bf16(a1, b1, acc, 0, 0, 0);
            float bias = qb[nt * 16 + lo];
            if (nt < 8) {
#pragma unroll
                for (int r = 0; r < 4; r++) qkb[quad * 4 + r][nt * 16 + lo] = f2bu(acc[r] + bias);
            } else {
#pragma unroll
                for (int r = 0; r < 4; r++) vt[(nt - 8) * 16 + lo][quad * 4 + r] = f2bu(acc[r] + bias);
            }
        }

        short8 zf = {0, 0, 0, 0, 0, 0, 0, 0};
        // scores + softmax: no max-subtraction (|scores| <~ 6, fp32 exp safe);
        // row-sum via DPP row_ror (VALU pipe) instead of LDS shfl butterfly.
#pragma unroll
        for (int h = 0; h < 4; h++) {
            short8 qf = zf, kf = zf;
            if (quad < 2) {
                qf = *(const short8*)&qkb[lo][h * 16 + quad * 8];
                kf = *(const short8*)&qkb[lo][64 + h * 16 + quad * 8];
            }
            f32x4 s4 = {0.f, 0.f, 0.f, 0.f};
            s4 = __builtin_amdgcn_mfma_f32_16x16x32_bf16(qf, kf, s4, 0, 0, 0);
#pragma unroll
            for (int r = 0; r < 4; r++) {
                float e = __expf(s4[r] * 0.25f + adjr[r]);
                float sm = dpp_row_sum16(e);
                qkb[quad * 4 + r][h * 16 + lo] = f2bu(e / sm);
            }
        }
#pragma unroll
        for (int h = 0; h < 4; h++) {
            short8 pf = zf, vf = zf;
            if (quad < 2) {
                pf = *(const short8*)&qkb[lo][h * 16 + quad * 8];
                vf = *(const short8*)&vt[h * 16 + lo][quad * 8];
            }
            f32x4 oc = {0.f, 0.f, 0.f, 0.f};
            oc = __builtin_amdgcn_mfma_f32_16x16x32_bf16(pf, vf, oc, 0, 0, 0);
#pragma unroll
            for (int r = 0; r < 4; r++) qkb[quad * 4 + r][h * 16 + lo] = f2bu(oc[r]);
        }
        short8 pa0 = *(const short8*)&qkb[lo][quad * 8];
        short8 pa1 = *(const short8*)&qkb[lo][32 + quad * 8];
#pragma unroll
        for (int nt = 0; nt < 4; nt++) {
            const ushort_t* wr = wo + (nt * 16 + lo) * 64 + quad * 8;
            short8 b0 = *(const short8*)wr;
            short8 b1 = *(const short8*)(wr + 32);
            f32x4 acc = {0.f, 0.f, 0.f, 0.f};
            acc = __builtin_amdgcn_mfma_f32_16x16x32_bf16(pa0, b0, acc, 0, 0, 0);
            acc = __builtin_amdgcn_mfma_f32_16x16x32_bf16(pa1, b1, acc, 0, 0, 0);
            float bias = ob[nt * 16 + lo];
#pragma unroll
            for (int r = 0; r < 4; r++) htw[quad * 4 + r][nt * 16 + lo] += acc[r] + bias;
        }
        short8 fa0, fa1;
        ln_frag(htw, n2g_ + layer * 64, n2b_ + layer * 64, quad, lo, fa0, fa1);
#pragma unroll
        for (int nt = 0; nt < 8; nt++) {
            const ushort_t* wr = wf1 + (nt * 16 + lo) * 64 + quad * 8;
            short8 b0 = *(const short8*)wr;
            short8 b1 = *(const short8*)(wr + 32);
            f32x4 acc = {0.f, 0.f, 0.f, 0.f};
            acc = __builtin_amdgcn_mfma_f32_16x16x32_bf16(fa0, b0, acc, 0, 0, 0);
            acc = __builtin_amdgcn_mfma_f32_16x16x32_bf16(fa1, b1, acc, 0, 0, 0);
            float bias = f1b[nt * 16 + lo];
#pragma unroll
            for (int r = 0; r < 4; r++) qkb[quad * 4 + r][nt * 16 + lo] = f2bu(geluf(acc[r] + bias));
        }
        short8 ga[4];
#pragma unroll
        for (int kb = 0; kb < 4; kb++) ga[kb] = *(const short8*)&qkb[lo][kb * 32 + quad * 8];
#pragma unroll
        for (int nt = 0; nt < 4; nt++) {
            const ushort_t* wr = wf2 + (nt * 16 + lo) * 128 + quad * 8;
            f32x4 acc = {0.f, 0.f, 0.f, 0.f};
#pragma unroll
            for (int kb = 0; kb < 4; kb++) {
                short8 bb = *(const short8*)(wr + kb * 32);
                acc = __builtin_amdgcn_mfma_f32_16x16x32_bf16(ga[kb], bb, acc, 0, 0, 0);
            }
            float bias = f2b[nt * 16 + lo];
#pragma unroll
            for (int r = 0; r < 4; r++) htw[quad * 4 + r][nt * 16 + lo] += acc[r] + bias;
        }
    }
    // ---- final LN -> bf16 hmb ----
    {
        float v[16];
        const float4* r0 = (const float4*)(&htw[lo][quad * 8]);
        const float4* r1 = (const float4*)(&htw[lo][32 + quad * 8]);
        float4 p0 = r0[0], p1 = r0[1], p2 = r1[0], p3 = r1[1];
        v[0] = p0.x; v[1] = p0.y; v[2] = p0.z; v[3] = p0.w;
        v[4] = p1.x; v[5] = p1.y; v[6] = p1.z; v[7] = p1.w;
        v[8] = p2.x; v[9] = p2.y; v[10] = p2.z; v[11] = p2.w;
        v[12] = p3.x; v[13] = p3.y; v[14] = p3.z; v[15] = p3.w;
        float s = 0.f;
#pragma unroll
        for (int i = 0; i < 16; i++) s += v[i];
        s += __shfl_xor(s, 16); s += __shfl_xor(s, 32);
        float mean = s * (1.0f / 64.0f);
        float q = 0.f;
#pragma unroll
        for (int i = 0; i < 16; i++) { float d = v[i] - mean; q += d * d; }
        q += __shfl_xor(q, 16); q += __shfl_xor(q, 32);
        float rstd = rsqrtf(q * (1.0f / 64.0f) + 1e-5f);
        float4 g0 = *(const float4*)(gng + quad * 8);
        float4 g1 = *(const float4*)(gng + quad * 8 + 4);
        float4 g2 = *(const float4*)(gng + 32 + quad * 8);
        float4 g3 = *(const float4*)(gng + 32 + quad * 8 + 4);
        float4 b0 = *(const float4*)(gnb + quad * 8);
        float4 b1 = *(const float4*)(gnb + quad * 8 + 4);
        float4 b2 = *(const float4*)(gnb + 32 + quad * 8);
        float4 b3 = *(const float4*)(gnb + 32 + quad * 8 + 4);
        float gg[16] = {g0.x, g0.y, g0.z, g0.w, g1.x, g1.y, g1.z, g1.w,
                        g2.x, g2.y, g2.z, g2.w, g3.x, g3.y, g3.z, g3.w};
        float bb[16] = {b0.x, b0.y, b0.z, b0.w, b1.x, b1.y, b1.z, b1.w,
                        b2.x, b2.y, b2.z, b2.w, b3.x, b3.y, b3.z, b3.w};
        unsigned u[8];
#pragma unroll
        for (int i = 0; i < 4; i++) {
            float oa = (v[2 * i] - mean) * rstd * gg[2 * i] + bb[2 * i];
            float obv = (v[2 * i + 1] - mean) * rstd * gg[2 * i + 1] + bb[2 * i + 1];
            u[i] = pack2bf(oa, obv);
            float oc = (v[8 + 2 * i] - mean) * rstd * gg[8 + 2 * i] + bb[8 + 2 * i];
            float od = (v[9 + 2 * i] - mean) * rstd * gg[9 + 2 * i] + bb[9 + 2 * i];
            u[4 + i] = pack2bf(oc, od);
        }
        ushort_t* dst = hmb + (size_t)(b * 16 + lo) * 16384 + (size_t)tp * 64;
        *(uint4*)(dst + quad * 8) = make_uint4(u[0], u[1], u[2], u[3]);
        *(uint4*)(dst + 32 + quad * 8) = make_uint4(u[4], u[5], u[6], u[7]);
    }
}

// =============================== K6: GRU (MFMA, W-as-A) ======================
__global__ __launch_bounds__(256) void k_gru(
    const ushort_t* __restrict__ hmb, const ushort_t* __restrict__ wgru,
    const float* __restrict__ bih_, const float* __restrict__ bhh_,
    float* __restrict__ h_out)
{
    __shared__ ushort_t hbuf[2][16][72];
    int t = threadIdx.x;
    int w = t >> 6, l = t & 63;
    int lo = l & 15, qd = l >> 4;
    int dir = blockIdx.x >> 5;
    int cseq0 = (blockIdx.x & 31) * 16;
    const ushort_t* wih = wgru + dir * 12288;
    const ushort_t* whh = wgru + 24576 + dir * 12288;
    const ushort_t* pr0 = wih + ((w) * 16 + lo) * 64 + qd * 8;
    const ushort_t* pz0 = wih + ((4 + w) * 16 + lo) * 64 + qd * 8;
    const ushort_t* pn0 = wih + ((8 + w) * 16 + lo) * 64 + qd * 8;
    const ushort_t* hr0 = whh + ((w) * 16 + lo) * 64 + qd * 8;
    const ushort_t* hz0 = whh + ((4 + w) * 16 + lo) * 64 + qd * 8;
    const ushort_t* hn0 = whh + ((8 + w) * 16 + lo) * 64 + qd * 8;
    short8 wi_r0 = *(const short8*)pr0, wi_r1 = *(const short8*)(pr0 + 32);
    short8 wi_z0 = *(const short8*)pz0, wi_z1 = *(const short8*)(pz0 + 32);
    short8 wi_n0 = *(const short8*)pn0, wi_n1 = *(const short8*)(pn0 + 32);
    short8 wh_r0 = *(const short8*)hr0, wh_r1 = *(const short8*)(hr0 + 32);
    short8 wh_z0 = *(const short8*)hz0, wh_z1 = *(const short8*)(hz0 + 32);
    short8 wh_n0 = *(const short8*)hn0, wh_n1 = *(const short8*)(hn0 + 32);
    int d_base = w * 16 + qd * 4;
    float bsr[4], bsz[4], bin[4], bhn[4];
#pragma unroll
    for (int r = 0; r < 4; r++) {
        bsr[r] = bih_[dir * 192 + d_base + r] + bhh_[dir * 192 + d_base + r];
        bsz[r] = bih_[dir * 192 + 64 + d_base + r] + bhh_[dir * 192 + 64 + d_base + r];
        bin[r] = bih_[dir * 192 + 128 + d_base + r];
        bhn[r] = bhh_[dir * 192 + 128 + d_base + r];
    }
    const ushort_t* xrow = hmb + (size_t)(cseq0 + lo) * 16384 + qd * 8;
    for (int i = t; i < 2 * 16 * 72; i += 256) ((ushort_t*)hbuf)[i] = 0;
    float h_old[4] = {0.f, 0.f, 0.f, 0.f};

    int s0 = dir ? 255 : 0;
    int s1 = dir ? 254 : 1;
    int s2 = dir ? 253 : 2;
    short8 xc0 = *(const short8*)(xrow + s0 * 64);
    short8 xc1 = *(const short8*)(xrow + s0 * 64 + 32);
    short8 xA0 = *(const short8*)(xrow + s1 * 64);
    short8 xA1 = *(const short8*)(xrow + s1 * 64 + 32);
    short8 xB0 = *(const short8*)(xrow + s2 * 64);
    short8 xB1 = *(const short8*)(xrow + s2 * 64 + 32);
    f32x4 axr = {0.f, 0.f, 0.f, 0.f}, axz = {0.f, 0.f, 0.f, 0.f}, axn = {0.f, 0.f, 0.f, 0.f};
    axr = __builtin_amdgcn_mfma_f32_16x16x32_bf16(wi_r0, xc0, axr, 0, 0, 0);
    axr = __builtin_amdgcn_mfma_f32_16x16x32_bf16(wi_r1, xc1, axr, 0, 0, 0);
    axz = __builtin_amdgcn_mfma_f32_16x16x32_bf16(wi_z0, xc0, axz, 0, 0, 0);
    axz = __builtin_amdgcn_mfma_f32_16x16x32_bf16(wi_z1, xc1, axz, 0, 0, 0);
    axn = __builtin_amdgcn_mfma_f32_16x16x32_bf16(wi_n0, xc0, axn, 0, 0, 0);
    axn = __builtin_amdgcn_mfma_f32_16x16x32_bf16(wi_n1, xc1, axn, 0, 0, 0);
    __syncthreads();
#pragma unroll 2
    for (int step = 0; step < 256; step++) {
        int cur = step & 1, nxt = cur ^ 1;
        f32x4 nxr = {0.f, 0.f, 0.f, 0.f}, nxz = {0.f, 0.f, 0.f, 0.f}, nxn = {0.f, 0.f, 0.f, 0.f};
        nxr = __builtin_amdgcn_mfma_f32_16x16x32_bf16(wi_r0, xA0, nxr, 0, 0, 0);
        nxr = __builtin_amdgcn_mfma_f32_16x16x32_bf16(wi_r1, xA1, nxr, 0, 0, 0);
        nxz = __builtin_amdgcn_mfma_f32_16x16x32_bf16(wi_z0, xA0, nxz, 0, 0, 0);
        nxz = __builtin_amdgcn_mfma_f32_16x16x32_bf16(wi_z1, xA1, nxz, 0, 0, 0);
        nxn = __builtin_amdgcn_mfma_f32_16x16x32_bf16(wi_n0, xA0, nxn, 0, 0, 0);
        nxn = __builtin_amdgcn_mfma_f32_16x16x32_bf16(wi_n1, xA1, nxn, 0, 0, 0);
        xA0 = xB0; xA1 = xB1;
        int tl = step + 3 > 255 ? 255 : step + 3;
        int sf = dir ? 255 - tl : tl;
        xB0 = *(const short8*)(xrow + sf * 64);
        xB1 = *(const short8*)(xrow + sf * 64 + 32);
        short8 bh0 = *(const short8*)&hbuf[cur][lo][qd * 8];
        short8 bh1 = *(const short8*)&hbuf[cur][lo][32 + qd * 8];
        f32x4 ar = axr, az = axz;
        f32x4 anh = {0.f, 0.f, 0.f, 0.f};
        ar = __builtin_amdgcn_mfma_f32_16x16x32_bf16(wh_r0, bh0, ar, 0, 0, 0);
        ar = __builtin_amdgcn_mfma_f32_16x16x32_bf16(wh_r1, bh1, ar, 0, 0, 0);
        az = __builtin_amdgcn_mfma_f32_16x16x32_bf16(wh_z0, bh0, az, 0, 0, 0);
        az = __builtin_amdgcn_mfma_f32_16x16x32_bf16(wh_z1, bh1, az, 0, 0, 0);
        anh = __builtin_amdgcn_mfma_f32_16x16x32_bf16(wh_n0, bh0, anh, 0, 0, 0);
        anh = __builtin_amdgcn_mfma_f32_16x16x32_bf16(wh_n1, bh1, anh, 0, 0, 0);
        float hv[4];
#pragma unroll
        for (int r = 0; r < 4; r++) {
            float gr = sigmoidf_(ar[r] + bsr[r]);
            float gz = sigmoidf_(az[r] + bsz[r]);
            float nin = (axn[r] + bin[r]) + gr * (anh[r] + bhn[r]);
            nin = fminf(fmaxf(nin, -15.f), 15.f);
            float e = __expf(-2.f * nin);
            float gn = (1.f - e) / (1.f + e);
            float hn = gn + gz * (h_old[r] - gn);
            h_old[r] = hn;
            hv[r] = hn;
        }
        *(uint2*)&hbuf[nxt][lo][d_base] = make_uint2(pack2bf(hv[0], hv[1]), pack2bf(hv[2], hv[3]));
        asm volatile("s_waitcnt lgkmcnt(0)\n\ts_barrier" ::: "memory");
        axr = nxr; axz = nxz; axn = nxn;
    }
    *(float4*)&h_out[(size_t)(cseq0 + lo) * 128 + dir * 64 + d_base] =
        make_float4(h_old[0], h_old[1], h_old[2], h_old[3]);
}

// =============================== K7: readout =================================
__global__ __launch_bounds__(128) void k_readout(
    const float* __restrict__ h_out, const float* __restrict__ gw, const float* __restrict__ gb,
    void* __restrict__ out, const int* __restrict__ flag)
{
    __shared__ float gate_s[16];
    __shared__ float gws[128];
    int b = blockIdx.x, t = threadIdx.x;
    gws[t] = gw[t];
    __syncthreads();
    int isb = *flag;
    if (t < 16) {
        const float* hr = h_out + (size_t)(b * 16 + t) * 128;
        float acc = gb[0];
        for (int k = 0; k < 128; k++) acc += hr[k] * gws[k];
        float g = sigmoidf_(acc);
        gate_s[t] = g;
        if (isb) ((bf16*)out)[12288 + b * 16 + t] = f2b(g);
        else     ((float*)out)[12288 + b * 16 + t] = g;
    }
    __syncthreads();
    float den = 1e-8f;
#pragma unroll
    for (int c = 0; c < 16; c++) den += gate_s[c];
    float num = 0.f;
#pragma unroll
    for (int c = 0; c < 16; c++) num += h_out[(size_t)(b * 16 + c) * 128 + t] * gate_s[c];
    float v = num / den;
    if (isb) ((bf16*)out)[b * 128 + t] = f2b(v);
    else     ((float*)out)[b * 128 + t] = v;
}

// =============================== launch ======================================
extern "C" void kernel_launch(void* const* d_in, const int* in_sizes, int n_in,
                              void* d_out, int out_size, void* d_ws, size_t ws_size,
                              hipStream_t stream)
{
    int* flag = (int*)d_ws;
    float* cvt = (float*)((char*)d_ws + 256);

    InPtrs P;
    InOffs O;
    int cum = 0;
    for (int i = 0; i < 35; i++) {
        P.p[i] = d_in[i];
        O.off[i] = cum;
        O.sz[i] = in_sizes[i];
        cum += (in_sizes[i] + 7) & ~7;
    }
    int total = cum;

    const float* x     = cvt + O.off[0];
    const float* c1w   = cvt + O.off[1];
    const float* c1b   = cvt + O.off[2];
    const float* bn1g  = cvt + O.off[3];
    const float* bn1b  = cvt + O.off[4];
    const float* bn1m  = cvt + O.off[5];
    const float* bn1v  = cvt + O.off[6];
    const float* c2w   = cvt + O.off[7];
    const float* c2b   = cvt + O.off[8];
    const float* bn2g  = cvt + O.off[9];
    const float* bn2b  = cvt + O.off[10];
    const float* bn2m  = cvt + O.off[11];
    const float* bn2v  = cvt + O.off[12];
    const float* prior = cvt + O.off[13];
    const float* logw  = cvt + O.off[14];
    const float* n1g   = cvt + O.off[15];
    const float* n1b   = cvt + O.off[16];
    const float* qkvw  = cvt + O.off[17];
    const float* qkvb  = cvt + O.off[18];
    const float* outw  = cvt + O.off[19];
    const float* outb  = cvt + O.off[20];
    const float* n2g   = cvt + O.off[21];
    const float* n2b   = cvt + O.off[22];
    const float* f1w   = cvt + O.off[23];
    const float* f1b   = cvt + O.off[24];
    const float* f2w   = cvt + O.off[25];
    const float* f2b_  = cvt + O.off[26];
    const float* gng   = cvt + O.off[27];
    const float* gnb   = cvt + O.off[28];
    const float* gwih  = cvt + O.off[29];
    const float* gwhh  = cvt + O.off[30];
    const float* gbih  = cvt + O.off[31];
    const float* gbhh  = cvt + O.off[32];
    const float* gatew = cvt + O.off[33];
    const float* gateb = cvt + O.off[34];

    float* fbase = cvt + ((total + 63) & ~63);
    float* hm    = fbase;                              // 8388608 floats (CNN out)
    ushort_t* Xnb = (ushort_t*)(hm + 8388608);         // 512*2080 bf16 spectrum
    float* hnf   = fbase + 8921088;                    // 32768
    float* adjw  = hnf + 32768;                        // 8192
    float* hout  = adjw + 8192;                        // 65536
    unsigned* wpk = (unsigned*)(hout + 65536);         // 62464 uints (bf16 weights)
    ushort_t* hmb = (ushort_t*)(wpk + 62464);          // 8388608 bf16 (GAT out)

    k_detect<<<1, 256, 0, stream>>>((const unsigned*)d_in[0], flag);
    k_convert<<<(total + 255) / 256, 256, 0, stream>>>(P, O, total, flag, cvt);
    k_pack<<<244, 256, 0, stream>>>(qkvw, outw, f1w, f2w, gwih, gwhh, c2w, wpk);
    k_front<<<768, 256, 0, stream>>>(x, c1w, c1b, bn1g, bn1b, bn1m, bn1v,
                                     c2b, bn2g, bn2b, bn2m, bn2v,
                                     (const ushort_t*)(wpk + 57344), hm, Xnb, hnf);
    k_adj<<<32, 256, 0, stream>>>(Xnb, hnf, prior, logw, adjw, d_out, flag);
    k_gat<<<2048, 256, 0, stream>>>(hm, adjw, (const ushort_t*)wpk,
                                    qkvb, outb, f1b, f2b_, n1g, n1b, n2g, n2b, gng, gnb, hmb);
    k_gru<<<64, 256, 0, stream>>>(hmb, (const ushort_t*)(wpk + 32768), gbih, gbhh, hout);
    k_readout<<<32, 128, 0, stream>>>(hout, gatew, gateb, d_out, flag);
}